// Round 8
// baseline (284.762 us; speedup 1.0000x reference)
//
#include <hip/hip_runtime.h>
#include <math.h>

#define NPIX 8192
#define DD 512
#define FF 32
#define NN 16384
#define HWS 1024
#define MARGIN 0.012f
#define NBLK 256

// ws layout (bytes); ws_size ~256MB
#define WS_KEYS64 0         // 8192*8
#define WS_KEYS32 65536     // 8192*4
#define WS_COUNTS 98304     // 16384*4
#define WS_MISC   163840    // f32[0]=loss acc; f32[1]=entropy acc; u32[2]=done; u32[16]=bar_cnt; u32[32]=bar_gen
#define WS_EN     229632    // 2 MB fp32 normalized codebook
#define WS_EH     2326784   // 1 MB tile-major bf16-h codebook (stream overread spills into WS_X: harmless)
#define WS_X      3375360   // 1 MB fp32 normalized x
#define WS_XH     4423936   // 512 KB bf16-h x fragments
#define WS_PART   4948224   // 32*8192*32*4 = 32 MB

typedef __bf16 bf16x8 __attribute__((ext_vector_type(8)));
typedef float f32x4 __attribute__((ext_vector_type(4)));
typedef unsigned int uint32x4 __attribute__((ext_vector_type(4)));

__device__ __forceinline__ unsigned short bf16_rne(float f) {
    unsigned u = __float_as_uint(f);
    u += 0x7fffu + ((u >> 16) & 1u);
    return (unsigned short)(u >> 16);
}
__device__ __forceinline__ f32x4 mfma16(bf16x8 a, bf16x8 b, f32x4 c) {
    return __builtin_amdgcn_mfma_f32_16x16x32_bf16(a, b, c, 0, 0, 0);
}
__device__ __forceinline__ unsigned mono_u32(float v) {
    unsigned u = __float_as_uint(v);
    return (u & 0x80000000u) ? ~u : (u | 0x80000000u);
}
__device__ __forceinline__ float mono_dec(unsigned u) {
    return __uint_as_float((u & 0x80000000u) ? (u ^ 0x80000000u) : ~u);
}
__device__ __forceinline__ unsigned long long packkey(float v, int n) {
    return ((unsigned long long)mono_u32(v) << 32) | (unsigned long long)(~(unsigned)n);
}

// sense-reversing grid barrier (R7-proven); works with arbitrary persistent gen,
// requires cnt==0 at launch (vq_init).
__device__ __forceinline__ void gbar(unsigned* cnt, unsigned* gen) {
    __syncthreads();
    if (threadIdx.x == 0) {
        unsigned g = __hip_atomic_load(gen, __ATOMIC_RELAXED, __HIP_MEMORY_SCOPE_AGENT);
        unsigned old = __hip_atomic_fetch_add(cnt, 1, __ATOMIC_ACQ_REL, __HIP_MEMORY_SCOPE_AGENT);
        if (old == NBLK - 1) {
            __hip_atomic_store(cnt, 0u, __ATOMIC_RELAXED, __HIP_MEMORY_SCOPE_AGENT);
            __hip_atomic_fetch_add(gen, 1, __ATOMIC_ACQ_REL, __HIP_MEMORY_SCOPE_AGENT);
        } else {
            while (__hip_atomic_load(gen, __ATOMIC_ACQUIRE, __HIP_MEMORY_SCOPE_AGENT) == g)
                __builtin_amdgcn_s_sleep(2);
        }
    }
    __syncthreads();
}

// zero-init + codebook l2-norm (EN fp32, EH bf16-h tile-major). 64 blocks x 256.
__global__ __launch_bounds__(256) void vq_init(const float* __restrict__ emb, char* __restrict__ ws) {
    int i = blockIdx.x * 256 + threadIdx.x;        // 0..16383
    ((int*)(ws + WS_COUNTS))[i] = 0;
    if (i < 8192) {
        ((unsigned long long*)(ws + WS_KEYS64))[i] = 0ull;
        ((unsigned*)(ws + WS_KEYS32))[i] = 0u;
    }
    if (i < 64) ((unsigned*)(ws + WS_MISC))[i] = 0u;

    float* EN = (float*)(ws + WS_EN);
    char*  EH = ws + WS_EH;
    const float4* r = (const float4*)(emb + (size_t)i * FF);
    float e[FF];
    float s = 0.f;
#pragma unroll
    for (int q = 0; q < 8; q++) {
        float4 v = r[q];
        e[q * 4] = v.x; e[q * 4 + 1] = v.y; e[q * 4 + 2] = v.z; e[q * 4 + 3] = v.w;
        s += v.x * v.x + v.y * v.y + v.z * v.z + v.w * v.w;
    }
    float m = fmaxf(sqrtf(s), 1e-6f);
#pragma unroll
    for (int f = 0; f < FF; f++) e[f] = e[f] / m;
    float4* o = (float4*)(EN + (size_t)i * FF);
#pragma unroll
    for (int q = 0; q < 8; q++)
        o[q] = make_float4(e[q * 4], e[q * 4 + 1], e[q * 4 + 2], e[q * 4 + 3]);
    int g = i >> 4, rl = i & 15;
#pragma unroll
    for (int kg = 0; kg < 4; kg++) {
        unsigned hw_[4];
#pragma unroll
        for (int w = 0; w < 4; w++) {
            unsigned short h0 = bf16_rne(e[kg * 8 + w * 2]);
            unsigned short h1 = bf16_rne(e[kg * 8 + w * 2 + 1]);
            hw_[w] = (unsigned)h0 | ((unsigned)h1 << 16);
        }
        uint32x4 th = {hw_[0], hw_[1], hw_[2], hw_[3]};
        *(uint32x4*)(EH + (size_t)g * 1024 + (kg * 16 + rl) * 16) = th;
    }
}

// Persistent phases at 16 waves/CU: 256 blocks x 1024 threads, vsub = bx*4 + (tid>>8).
__global__ __launch_bounds__(1024, 4) void vq_mono(const float* __restrict__ enc,
                                                   const float* __restrict__ pw, const float* __restrict__ pbias,
                                                   const float* __restrict__ ew, const float* __restrict__ eb,
                                                   float* __restrict__ out, char* __restrict__ ws) {
    __shared__ float lds[4][1024];
    unsigned long long* keys64 = (unsigned long long*)(ws + WS_KEYS64);
    unsigned* keys32 = (unsigned*)(ws + WS_KEYS32);
    int*   counts = (int*)(ws + WS_COUNTS);
    float* misc   = (float*)(ws + WS_MISC);
    unsigned* done = (unsigned*)(ws + WS_MISC) + 2;
    unsigned* bcnt = (unsigned*)(ws + WS_MISC) + 16;
    unsigned* bgen = (unsigned*)(ws + WS_MISC) + 32;
    float* EN     = (float*)(ws + WS_EN);
    char*  EH     = ws + WS_EH;
    float* X      = (float*)(ws + WS_X);
    char*  XH     = ws + WS_XH;
    float* part   = (float*)(ws + WS_PART);
    int bx = blockIdx.x, tid = threadIdx.x;
    int sub = tid >> 8, stid = tid & 255;
    int vsub = bx * 4 + sub;

    // ---- P0a: proj partials. vsub = (ds 0..15) * 64 + (pb 0..63). thread: 1 px, 16 d. ----
    {
        int pb = vsub & 63, ds = vsub >> 6;
        int d0b = ds * 32;
        for (int i = stid; i < 1024; i += 256) {
            int dl = i >> 5, f = i & 31;
            lds[sub][dl * 32 + f] = pw[f * DD + d0b + dl];   // transpose folded into stage
        }
        __syncthreads();
        int px = pb * 128 + (stid & 127);
        int dh = stid >> 7;
        int d0 = d0b + dh * 16;
        int b = px >> 10, hw = px & 1023;
        const float* ep = enc + (size_t)b * DD * HWS + (size_t)d0 * HWS + hw;
        float acc[FF];
#pragma unroll
        for (int f = 0; f < FF; f++) acc[f] = 0.f;
        float ev[4];
#pragma unroll
        for (int j = 0; j < 4; j++) ev[j] = ep[(size_t)j * HWS];
#pragma unroll
        for (int g = 0; g < 4; g++) {
            float nv[4];
            if (g < 3) {
#pragma unroll
                for (int j = 0; j < 4; j++) nv[j] = ep[(size_t)(g * 4 + 4 + j) * HWS];
            }
#pragma unroll
            for (int j = 0; j < 4; j++) {
                const float4* w4 = (const float4*)&lds[sub][(dh * 16 + g * 4 + j) * 32];
#pragma unroll
                for (int q = 0; q < 8; q++) {
                    float4 w = w4[q];
                    acc[q * 4 + 0] = fmaf(ev[j], w.x, acc[q * 4 + 0]);
                    acc[q * 4 + 1] = fmaf(ev[j], w.y, acc[q * 4 + 1]);
                    acc[q * 4 + 2] = fmaf(ev[j], w.z, acc[q * 4 + 2]);
                    acc[q * 4 + 3] = fmaf(ev[j], w.w, acc[q * 4 + 3]);
                }
            }
            if (g < 3) {
#pragma unroll
                for (int j = 0; j < 4; j++) ev[j] = nv[j];
            }
        }
        int seg = ds * 2 + dh;
        float4* o = (float4*)(part + ((size_t)seg * NPIX + px) * FF);
#pragma unroll
        for (int q = 0; q < 8; q++)
            o[q] = make_float4(acc[q * 4], acc[q * 4 + 1], acc[q * 4 + 2], acc[q * 4 + 3]);
    }
    gbar(bcnt, bgen);

    // ---- P0b: finish x (32 threads/pixel, 1 ch each; 262144 threads exactly) ----
    {
        int t = bx * 1024 + tid;
        int px = t >> 5, ch = t & 31;
        float a = 0.f;
        for (int sg = 0; sg < 32; sg++)
            a += part[((size_t)sg * NPIX + px) * FF + ch];
        a += pbias[ch];
        float ss = a * a;
        ss += __shfl_xor(ss, 1);
        ss += __shfl_xor(ss, 2);
        ss += __shfl_xor(ss, 4);
        ss += __shfl_xor(ss, 8);
        ss += __shfl_xor(ss, 16);
        float m = fmaxf(sqrtf(ss), 1e-6f);
        a /= m;
        X[(size_t)px * FF + ch] = a;
        unsigned hs = (unsigned)bf16_rne(a);
        unsigned hp = __shfl_xor(hs, 1);
        if (!(ch & 1)) *(unsigned*)(XH + (size_t)px * 64 + ch * 2) = hs | (hp << 16);
    }
    gbar(bcnt, bgen);

    // ---- P2: approx argmax (h.h MFMA) -> keys32 global per-pixel max ----
    {
        int lane = tid & 63, wv = (tid >> 6) & 3, rl = lane & 15, kg = lane >> 4;
        int mblk = vsub & 31, nblk = vsub >> 5;
        int wavebase = mblk * 256 + wv * 64;
        const uint32x4* XHp = (const uint32x4*)XH;
        bf16x8 ah[4];
#pragma unroll
        for (int m = 0; m < 4; m++)
            ah[m] = __builtin_bit_cast(bf16x8, XHp[(wavebase + m * 16 + rl) * 4 + kg]);
        const char* ebp = EH + (size_t)nblk * 32768 + lane * 16;
        float bv[16];
#pragma unroll
        for (int j = 0; j < 16; j++) bv[j] = -3.0e38f;
        uint32x4 s0 = *(const uint32x4*)(ebp);
        uint32x4 s1 = *(const uint32x4*)(ebp + 1024);
        uint32x4 s2 = *(const uint32x4*)(ebp + 2048);
        uint32x4 s3 = *(const uint32x4*)(ebp + 3072);
        for (int t = 0; t < 32; t += 2) {
            uint32x4 n0 = *(const uint32x4*)(ebp + (t + 4) * 1024);   // overread <=4KB: harmless
            uint32x4 n1 = *(const uint32x4*)(ebp + (t + 5) * 1024);
            bf16x8 bhA = __builtin_bit_cast(bf16x8, s0);
            bf16x8 bhB = __builtin_bit_cast(bf16x8, s1);
            f32x4 z = {0.f, 0.f, 0.f, 0.f};
            f32x4 a0 = mfma16(ah[0], bhA, z), a1 = mfma16(ah[1], bhA, z);
            f32x4 a2 = mfma16(ah[2], bhA, z), a3 = mfma16(ah[3], bhA, z);
            f32x4 b0 = mfma16(ah[0], bhB, z), b1 = mfma16(ah[1], bhB, z);
            f32x4 b2 = mfma16(ah[2], bhB, z), b3 = mfma16(ah[3], bhB, z);
#pragma unroll
            for (int i = 0; i < 4; i++) {
                bv[i]      = fmaxf(fmaxf(a0[i], b0[i]), bv[i]);
                bv[4 + i]  = fmaxf(fmaxf(a1[i], b1[i]), bv[4 + i]);
                bv[8 + i]  = fmaxf(fmaxf(a2[i], b2[i]), bv[8 + i]);
                bv[12 + i] = fmaxf(fmaxf(a3[i], b3[i]), bv[12 + i]);
            }
            s0 = s2; s1 = s3; s2 = n0; s3 = n1;
        }
#pragma unroll
        for (int st = 1; st < 16; st <<= 1)
#pragma unroll
            for (int j = 0; j < 16; j++) bv[j] = fmaxf(bv[j], __shfl_xor(bv[j], st));
        if (rl == 0) {
#pragma unroll
            for (int j = 0; j < 16; j++)
                atomicMax(keys32 + wavebase + (j >> 2) * 16 + kg * 4 + (j & 3), mono_u32(bv[j]));
        }
    }
    gbar(bcnt, bgen);

    // ---- P3: exact re-scan, accumulator seeded with C=-thr (candidate = c>=0) ----
    {
        int lane = tid & 63, wv = (tid >> 6) & 3, rl = lane & 15, kg = lane >> 4;
        int mblk = vsub & 31, nblk = vsub >> 5;
        int wavebase = mblk * 256 + wv * 64;
        const uint32x4* XHp = (const uint32x4*)XH;
        bf16x8 ah[4];
#pragma unroll
        for (int m = 0; m < 4; m++)
            ah[m] = __builtin_bit_cast(bf16x8, XHp[(wavebase + m * 16 + rl) * 4 + kg]);
        float nt[16];
#pragma unroll
        for (int j = 0; j < 16; j++)
            nt[j] = MARGIN - mono_dec(keys32[wavebase + (j >> 2) * 16 + kg * 4 + (j & 3)]);
        f32x4 ci0 = {nt[0], nt[1], nt[2], nt[3]};
        f32x4 ci1 = {nt[4], nt[5], nt[6], nt[7]};
        f32x4 ci2 = {nt[8], nt[9], nt[10], nt[11]};
        f32x4 ci3 = {nt[12], nt[13], nt[14], nt[15]};
        const char* ebp = EH + (size_t)nblk * 32768 + lane * 16;
        uint32x4 s0 = *(const uint32x4*)(ebp);
        uint32x4 s1 = *(const uint32x4*)(ebp + 1024);
        uint32x4 s2 = *(const uint32x4*)(ebp + 2048);
        uint32x4 s3 = *(const uint32x4*)(ebp + 3072);
        for (int t = 0; t < 32; t += 2) {
            uint32x4 n0 = *(const uint32x4*)(ebp + (t + 4) * 1024);
            uint32x4 n1 = *(const uint32x4*)(ebp + (t + 5) * 1024);
#pragma unroll
            for (int half = 0; half < 2; half++) {
                bf16x8 bh = __builtin_bit_cast(bf16x8, half ? s1 : s0);
                int T = t + half;
                f32x4 c0 = mfma16(ah[0], bh, ci0);
                f32x4 c1 = mfma16(ah[1], bh, ci1);
                f32x4 c2 = mfma16(ah[2], bh, ci2);
                f32x4 c3 = mfma16(ah[3], bh, ci3);
                float dm = fmaxf(fmaxf(fmaxf(fmaxf(c0[0], c0[1]), fmaxf(c0[2], c0[3])),
                                       fmaxf(fmaxf(c1[0], c1[1]), fmaxf(c1[2], c1[3]))),
                                 fmaxf(fmaxf(fmaxf(c2[0], c2[1]), fmaxf(c2[2], c2[3])),
                                       fmaxf(fmaxf(c3[0], c3[1]), fmaxf(c3[2], c3[3]))));
                if (dm >= 0.f) {
                    float av[16];
#pragma unroll
                    for (int i = 0; i < 4; i++) {
                        av[i] = c0[i]; av[4 + i] = c1[i];
                        av[8 + i] = c2[i]; av[12 + i] = c3[i];
                    }
#pragma unroll
                    for (int j = 0; j < 16; j++) {
                        if (av[j] >= 0.f) {
                            int p = wavebase + (j >> 2) * 16 + kg * 4 + (j & 3);
                            int n = nblk * 512 + T * 16 + rl;
                            const float4* xr = (const float4*)(X + (size_t)p * FF);
                            const float4* er = (const float4*)(EN + (size_t)n * FF);
                            float a0 = 0.f, a1 = 0.f, a2 = 0.f, a3 = 0.f;
#pragma unroll
                            for (int q = 0; q < 8; q++) {
                                float4 xv = xr[q], ev = er[q];
                                a0 = fmaf(xv.x, ev.x, a0); a1 = fmaf(xv.y, ev.y, a1);
                                a2 = fmaf(xv.z, ev.z, a2); a3 = fmaf(xv.w, ev.w, a3);
                            }
                            float v = (a0 + a1) + (a2 + a3);
                            atomicMax(keys64 + p, packkey(v, n));
                        }
                    }
                }
            }
            s0 = s2; s1 = s3; s2 = n0; s3 = n1;
        }
    }
    gbar(bcnt, bgen);

    // ---- P4: expand GEMM + closest/hist/loss ----
    {
        int lane = tid & 63, wv = (tid >> 6) & 3;
        int pb2 = vsub & 127, dg = vsub >> 7;
        int p = pb2 * 64 + lane;
        unsigned n = ~(unsigned)(keys64[p]);
        float lat[FF];
        const float4* l4 = (const float4*)(EN + (size_t)n * FF);
#pragma unroll
        for (int q = 0; q < 8; q++) {
            float4 v = l4[q];
            lat[q * 4] = v.x; lat[q * 4 + 1] = v.y; lat[q * 4 + 2] = v.z; lat[q * 4 + 3] = v.w;
        }
        if (dg == 0 && wv == 0) {
            out[4194304 + p] = (float)n;
            atomicAdd(counts + n, 1);
            const float4* xr = (const float4*)(X + (size_t)p * FF);
            float s = 0.f;
#pragma unroll
            for (int q = 0; q < 8; q++) {
                float4 xv = xr[q];
                float dx = xv.x - lat[q * 4], dy = xv.y - lat[q * 4 + 1];
                float dz = xv.z - lat[q * 4 + 2], dw = xv.w - lat[q * 4 + 3];
                s += dx * dx + dy * dy + dz * dz + dw * dw;
            }
            for (int off = 32; off > 0; off >>= 1) s += __shfl_down(s, off);
            if (lane == 0) atomicAdd(misc, s);
        }
        int b = p >> 10, hw = p & 1023;
        float* op = out + (size_t)b * DD * HWS + hw;
        int d0 = dg * 64 + wv * 16;
        for (int i = 0; i < 16; i++) {
            int d = d0 + i;
            const float4* w4 = (const float4*)(ew + (size_t)d * FF);
            float4 w0 = w4[0], w1 = w4[1], w2 = w4[2], w3 = w4[3];
            float4 w5 = w4[4], w6 = w4[5], w7 = w4[6], w8 = w4[7];
            float a0 = fmaf(lat[0], w0.x, eb[d]);
            float a1 = lat[1] * w0.y;
            float a2 = lat[2] * w0.z;
            float a3 = lat[3] * w0.w;
            a0 = fmaf(lat[4],  w1.x, a0); a1 = fmaf(lat[5],  w1.y, a1); a2 = fmaf(lat[6],  w1.z, a2); a3 = fmaf(lat[7],  w1.w, a3);
            a0 = fmaf(lat[8],  w2.x, a0); a1 = fmaf(lat[9],  w2.y, a1); a2 = fmaf(lat[10], w2.z, a2); a3 = fmaf(lat[11], w2.w, a3);
            a0 = fmaf(lat[12], w3.x, a0); a1 = fmaf(lat[13], w3.y, a1); a2 = fmaf(lat[14], w3.z, a2); a3 = fmaf(lat[15], w3.w, a3);
            a0 = fmaf(lat[16], w5.x, a0); a1 = fmaf(lat[17], w5.y, a1); a2 = fmaf(lat[18], w5.z, a2); a3 = fmaf(lat[19], w5.w, a3);
            a0 = fmaf(lat[20], w6.x, a0); a1 = fmaf(lat[21], w6.y, a1); a2 = fmaf(lat[22], w6.z, a2); a3 = fmaf(lat[23], w6.w, a3);
            a0 = fmaf(lat[24], w7.x, a0); a1 = fmaf(lat[25], w7.y, a1); a2 = fmaf(lat[26], w7.z, a2); a3 = fmaf(lat[27], w7.w, a3);
            a0 = fmaf(lat[28], w8.x, a0); a1 = fmaf(lat[29], w8.y, a1); a2 = fmaf(lat[30], w8.z, a2); a3 = fmaf(lat[31], w8.w, a3);
            op[(size_t)d * HWS] = (a0 + a1) + (a2 + a3);
        }
    }
    gbar(bcnt, bgen);

    // ---- P5: entropy partials (blocks 0..15) + done-counter finalize ----
    if (bx < 16) {
        int gt = bx * 1024 + tid;   // 0..16383
        float u = (float)counts[gt] * (1.0f / 8192.0f);
        float s = u * logf(u + 1e-6f);
        for (int off = 32; off > 0; off >>= 1) s += __shfl_down(s, off);
        if ((tid & 63) == 0) atomicAdd(misc + 1, s);
        __syncthreads();
        if (tid == 0) {
            unsigned old = __hip_atomic_fetch_add(done, 1, __ATOMIC_ACQ_REL, __HIP_MEMORY_SCOPE_AGENT);
            if (old == 15) {
                out[4194304 + NPIX]     = misc[0] * (1.0f / 262144.0f);   // loss: mean over B*F*H*W
                out[4194304 + NPIX + 1] = expf(-misc[1]);                 // perplexity
            }
        }
    }
}

extern "C" void kernel_launch(void* const* d_in, const int* in_sizes, int n_in,
                              void* d_out, int out_size, void* d_ws, size_t ws_size,
                              hipStream_t stream) {
    const float* enc   = (const float*)d_in[0];
    const float* emb   = (const float*)d_in[1];
    const float* pw    = (const float*)d_in[2];
    const float* pbias = (const float*)d_in[3];
    const float* ew    = (const float*)d_in[4];
    const float* eb    = (const float*)d_in[5];
    float* out = (float*)d_out;
    char* ws = (char*)d_ws;

    vq_init<<<64, 256, 0, stream>>>(emb, ws);
    vq_mono<<<NBLK, 1024, 0, stream>>>(enc, pw, pbias, ew, eb, out, ws);
}

// Round 9
// 104.190 us; speedup vs baseline: 2.7331x; 2.7331x over previous
//
#include <hip/hip_runtime.h>
#include <math.h>

#define NPIX 8192
#define DD 512
#define FF 32
#define NN 16384
#define HWS 1024
#define DSPLIT 16
#define MARGIN 0.012f

// ws layout (bytes); ws_size ~256MB
#define WS_KEYS64 0         // 8192*8
#define WS_KEYS32 65536     // 8192*4
#define WS_COUNTS 98304     // 16384*4
#define WS_MISC   163840    // f32[0]=loss acc; u32[2]=done ticket (zeroed in prep)
#define WS_EN     229632    // 2 MB fp32 normalized codebook
#define WS_EH     2326784   // 1 MB tile-major bf16-h codebook (stream overread spills into WS_X: harmless)
#define WS_X      3375360   // 1 MB fp32 normalized x
#define WS_XH     4423936   // 512 KB bf16-h x fragments
#define WS_PART   4948224   // 16*8192*32*4 = 16 MB

typedef __bf16 bf16x8 __attribute__((ext_vector_type(8)));
typedef float f32x4 __attribute__((ext_vector_type(4)));
typedef unsigned int uint32x4 __attribute__((ext_vector_type(4)));

__device__ __forceinline__ unsigned short bf16_rne(float f) {
    unsigned u = __float_as_uint(f);
    u += 0x7fffu + ((u >> 16) & 1u);
    return (unsigned short)(u >> 16);
}
__device__ __forceinline__ f32x4 mfma16(bf16x8 a, bf16x8 b, f32x4 c) {
    return __builtin_amdgcn_mfma_f32_16x16x32_bf16(a, b, c, 0, 0, 0);
}
__device__ __forceinline__ unsigned mono_u32(float v) {
    unsigned u = __float_as_uint(v);
    return (u & 0x80000000u) ? ~u : (u | 0x80000000u);
}
__device__ __forceinline__ float mono_dec(unsigned u) {
    return __uint_as_float((u & 0x80000000u) ? (u ^ 0x80000000u) : ~u);
}
__device__ __forceinline__ unsigned long long packkey(float v, int n) {
    return ((unsigned long long)mono_u32(v) << 32) | (unsigned long long)(~(unsigned)n);
}

// Fused: blocks 0..511 = partial projection (pb = bx&31, ds = bx>>5, 32 d each);
// blocks 512..575 = codebook l2-norm (EN fp32 + EH bf16-h tile-major) + zero-init.
// Weights read as wave-uniform scalar loads (s_load, SMEM pipe) -- no LDS stage.
__global__ __launch_bounds__(256) void prep_proj(const float* __restrict__ pw, const float* __restrict__ emb,
                                                 const float* __restrict__ enc, float* __restrict__ part,
                                                 float* __restrict__ EN, char* __restrict__ EH,
                                                 unsigned long long* __restrict__ keys64,
                                                 unsigned* __restrict__ keys32, int* __restrict__ counts,
                                                 unsigned* __restrict__ misc_u) {
    int bx = blockIdx.x;
    if (bx < 512) {
        int pb = bx & 31, ds = bx >> 5;
        int d0 = ds * 32;
        int p = pb * 256 + threadIdx.x;
        int b = p >> 10, hw = p & 1023;
        const float* ep = enc + (size_t)b * DD * HWS + (size_t)d0 * HWS + hw;
        float acc[FF];
#pragma unroll
        for (int f = 0; f < FF; f++) acc[f] = 0.f;
        float ev[4];
#pragma unroll
        for (int j = 0; j < 4; j++) ev[j] = ep[(size_t)j * HWS];
#pragma unroll
        for (int g = 0; g < 8; g++) {
            float nv[4];
            if (g < 7) {
#pragma unroll
                for (int j = 0; j < 4; j++) nv[j] = ep[(size_t)(g * 4 + 4 + j) * HWS];
            }
#pragma unroll
            for (int j = 0; j < 4; j++) {
                int dabs = d0 + g * 4 + j;            // wave-uniform -> weight loads hit SMEM
#pragma unroll
                for (int q = 0; q < 8; q++) {
                    float wx = pw[(q * 4 + 0) * DD + dabs];
                    float wy = pw[(q * 4 + 1) * DD + dabs];
                    float wz = pw[(q * 4 + 2) * DD + dabs];
                    float ww = pw[(q * 4 + 3) * DD + dabs];
                    acc[q * 4 + 0] = fmaf(ev[j], wx, acc[q * 4 + 0]);
                    acc[q * 4 + 1] = fmaf(ev[j], wy, acc[q * 4 + 1]);
                    acc[q * 4 + 2] = fmaf(ev[j], wz, acc[q * 4 + 2]);
                    acc[q * 4 + 3] = fmaf(ev[j], ww, acc[q * 4 + 3]);
                }
            }
            if (g < 7) {
#pragma unroll
                for (int j = 0; j < 4; j++) ev[j] = nv[j];
            }
        }
        float4* o = (float4*)(part + ((size_t)ds * NPIX + p) * FF);
#pragma unroll
        for (int q = 0; q < 8; q++)
            o[q] = make_float4(acc[q * 4], acc[q * 4 + 1], acc[q * 4 + 2], acc[q * 4 + 3]);
    } else {
        int i = (bx - 512) * 256 + threadIdx.x;   // 0..16383
        counts[i] = 0;
        if (i < 8192) { keys64[i] = 0ull; keys32[i] = 0u; }
        if (i < 8) misc_u[i] = 0u;
        const float4* r = (const float4*)(emb + (size_t)i * FF);
        float e[FF];
        float s = 0.f;
#pragma unroll
        for (int q = 0; q < 8; q++) {
            float4 v = r[q];
            e[q * 4] = v.x; e[q * 4 + 1] = v.y; e[q * 4 + 2] = v.z; e[q * 4 + 3] = v.w;
            s += v.x * v.x + v.y * v.y + v.z * v.z + v.w * v.w;
        }
        float m = fmaxf(sqrtf(s), 1e-6f);
#pragma unroll
        for (int f = 0; f < FF; f++) e[f] = e[f] / m;
        float4* o = (float4*)(EN + (size_t)i * FF);
#pragma unroll
        for (int q = 0; q < 8; q++)
            o[q] = make_float4(e[q * 4], e[q * 4 + 1], e[q * 4 + 2], e[q * 4 + 3]);
        int g = i >> 4, rl = i & 15;
#pragma unroll
        for (int kg = 0; kg < 4; kg++) {
            unsigned hw_[4];
#pragma unroll
            for (int w = 0; w < 4; w++) {
                unsigned short h0 = bf16_rne(e[kg * 8 + w * 2]);
                unsigned short h1 = bf16_rne(e[kg * 8 + w * 2 + 1]);
                hw_[w] = (unsigned)h0 | ((unsigned)h1 << 16);
            }
            uint32x4 th = {hw_[0], hw_[1], hw_[2], hw_[3]};
            *(uint32x4*)(EH + (size_t)g * 1024 + (kg * 16 + rl) * 16) = th;
        }
    }
}

// Sum partials + bias, l2norm -> X fp32 + bf16-h XH. 8 threads/pixel (4 ch each), 256 blocks.
__global__ __launch_bounds__(256) void finish_x(const float* __restrict__ part, const float* __restrict__ pbias,
                                                float* __restrict__ X, char* __restrict__ XH) {
    int t = blockIdx.x * 256 + threadIdx.x;
    int p = t >> 3, q = t & 7;
    float ax = 0.f, ay = 0.f, az = 0.f, aw = 0.f;
    for (int sg = 0; sg < DSPLIT; sg++) {
        float4 v = *(const float4*)(part + ((size_t)sg * NPIX + p) * FF + q * 4);
        ax += v.x; ay += v.y; az += v.z; aw += v.w;
    }
    float4 bq = *(const float4*)(pbias + q * 4);
    ax += bq.x; ay += bq.y; az += bq.z; aw += bq.w;
    float ss = ax * ax + ay * ay + az * az + aw * aw;
    ss += __shfl_xor(ss, 1);
    ss += __shfl_xor(ss, 2);
    ss += __shfl_xor(ss, 4);
    float m = fmaxf(sqrtf(ss), 1e-6f);
    ax /= m; ay /= m; az /= m; aw /= m;
    *(float4*)(X + (size_t)p * FF + q * 4) = make_float4(ax, ay, az, aw);
    unsigned h0 = (unsigned)bf16_rne(ax) | ((unsigned)bf16_rne(ay) << 16);
    unsigned h1 = (unsigned)bf16_rne(az) | ((unsigned)bf16_rne(aw) << 16);
    *(uint2*)(XH + (size_t)p * 64 + q * 8) = make_uint2(h0, h1);
}

// Phase 1: approx sims (h.h only) -> per-pixel max value via u32 atomicMax. (R4-proven)
#define APPROX_TILE(S)                                          \
    {                                                           \
        bf16x8 bh = __builtin_bit_cast(bf16x8, S);              \
        f32x4 c0 = {0.f,0.f,0.f,0.f}, c1 = {0.f,0.f,0.f,0.f};   \
        f32x4 c2 = {0.f,0.f,0.f,0.f}, c3 = {0.f,0.f,0.f,0.f};   \
        c0 = mfma16(ah[0], bh, c0); c1 = mfma16(ah[1], bh, c1); \
        c2 = mfma16(ah[2], bh, c2); c3 = mfma16(ah[3], bh, c3); \
        _Pragma("unroll")                                       \
        for (int i = 0; i < 4; i++) {                           \
            bv[i]      = fmaxf(bv[i],      c0[i]);              \
            bv[4 + i]  = fmaxf(bv[4 + i],  c1[i]);              \
            bv[8 + i]  = fmaxf(bv[8 + i],  c2[i]);              \
            bv[12 + i] = fmaxf(bv[12 + i], c3[i]);              \
        }                                                       \
    }

__global__ __launch_bounds__(256) void argmax_approx(const uint32x4* __restrict__ XHp,
                                                     const char* __restrict__ EH,
                                                     unsigned* __restrict__ keys32) {
    int tid = threadIdx.x, lane = tid & 63, wv = tid >> 6;
    int rl = lane & 15, kg = lane >> 4;
    int wavebase = blockIdx.x * 256 + wv * 64;
    int nblk = blockIdx.y;
    bf16x8 ah[4];
#pragma unroll
    for (int m = 0; m < 4; m++)
        ah[m] = __builtin_bit_cast(bf16x8, XHp[(wavebase + m * 16 + rl) * 4 + kg]);
    const char* pb = EH + (size_t)nblk * 32768 + lane * 16;
    float bv[16];
#pragma unroll
    for (int j = 0; j < 16; j++) bv[j] = -3.0e38f;

    uint32x4 s0 = *(const uint32x4*)(pb);
    uint32x4 s1 = *(const uint32x4*)(pb + 1024);
    uint32x4 s2 = *(const uint32x4*)(pb + 2048);
    uint32x4 s3 = *(const uint32x4*)(pb + 3072);
    for (int t = 0; t < 32; t += 2) {
        uint32x4 n0 = *(const uint32x4*)(pb + (t + 4) * 1024);   // overread <=4KB: harmless
        uint32x4 n1 = *(const uint32x4*)(pb + (t + 5) * 1024);
        APPROX_TILE(s0)
        APPROX_TILE(s1)
        s0 = s2; s1 = s3; s2 = n0; s3 = n1;
    }
#pragma unroll
    for (int st = 1; st < 16; st <<= 1)
#pragma unroll
        for (int j = 0; j < 16; j++) bv[j] = fmaxf(bv[j], __shfl_xor(bv[j], st));
    if (rl == 0) {
#pragma unroll
        for (int j = 0; j < 16; j++)
            atomicMax(keys32 + wavebase + (j >> 2) * 16 + kg * 4 + (j & 3), mono_u32(bv[j]));
    }
}

// Phase 2: recompute approx; candidates (>= pixelmax - MARGIN) get exact fp32 dot. (R4-proven)
#define EXACT_TILE(S, T)                                                          \
    {                                                                             \
        bf16x8 bh = __builtin_bit_cast(bf16x8, S);                                \
        f32x4 c0 = {0.f,0.f,0.f,0.f}, c1 = {0.f,0.f,0.f,0.f};                     \
        f32x4 c2 = {0.f,0.f,0.f,0.f}, c3 = {0.f,0.f,0.f,0.f};                     \
        c0 = mfma16(ah[0], bh, c0); c1 = mfma16(ah[1], bh, c1);                   \
        c2 = mfma16(ah[2], bh, c2); c3 = mfma16(ah[3], bh, c3);                   \
        float dm = c0[0] - thr[0];                                                \
        _Pragma("unroll")                                                         \
        for (int i = 0; i < 4; i++) {                                             \
            dm = fmaxf(dm, c0[i] - thr[i]);                                       \
            dm = fmaxf(dm, c1[i] - thr[4 + i]);                                   \
            dm = fmaxf(dm, c2[i] - thr[8 + i]);                                   \
            dm = fmaxf(dm, c3[i] - thr[12 + i]);                                  \
        }                                                                         \
        if (dm >= 0.f) {                                                          \
            float av[16];                                                         \
            _Pragma("unroll")                                                     \
            for (int i = 0; i < 4; i++) {                                         \
                av[i] = c0[i]; av[4 + i] = c1[i];                                 \
                av[8 + i] = c2[i]; av[12 + i] = c3[i];                            \
            }                                                                     \
            _Pragma("unroll")                                                     \
            for (int j = 0; j < 16; j++) {                                        \
                if (av[j] >= thr[j]) {                                            \
                    int p = wavebase + (j >> 2) * 16 + kg * 4 + (j & 3);          \
                    int n = nblk * 512 + (T) * 16 + rl;                           \
                    const float4* xr = (const float4*)(X + (size_t)p * FF);       \
                    const float4* er = (const float4*)(EN + (size_t)n * FF);      \
                    float a0 = 0.f, a1 = 0.f, a2 = 0.f, a3 = 0.f;                 \
                    _Pragma("unroll")                                             \
                    for (int q = 0; q < 8; q++) {                                 \
                        float4 xv = xr[q], ev = er[q];                            \
                        a0 = fmaf(xv.x, ev.x, a0); a1 = fmaf(xv.y, ev.y, a1);     \
                        a2 = fmaf(xv.z, ev.z, a2); a3 = fmaf(xv.w, ev.w, a3);     \
                    }                                                             \
                    float v = (a0 + a1) + (a2 + a3);                              \
                    atomicMax(keys64 + p, packkey(v, n));                         \
                }                                                                 \
            }                                                                     \
        }                                                                         \
    }

__global__ __launch_bounds__(256) void argmax_exact(const uint32x4* __restrict__ XHp,
                                                    const char* __restrict__ EH,
                                                    const unsigned* __restrict__ keys32,
                                                    const float* __restrict__ X, const float* __restrict__ EN,
                                                    unsigned long long* __restrict__ keys64) {
    int tid = threadIdx.x, lane = tid & 63, wv = tid >> 6;
    int rl = lane & 15, kg = lane >> 4;
    int wavebase = blockIdx.x * 256 + wv * 64;
    int nblk = blockIdx.y;
    bf16x8 ah[4];
#pragma unroll
    for (int m = 0; m < 4; m++)
        ah[m] = __builtin_bit_cast(bf16x8, XHp[(wavebase + m * 16 + rl) * 4 + kg]);
    float thr[16];
#pragma unroll
    for (int j = 0; j < 16; j++)
        thr[j] = mono_dec(keys32[wavebase + (j >> 2) * 16 + kg * 4 + (j & 3)]) - MARGIN;
    const char* pb = EH + (size_t)nblk * 32768 + lane * 16;

    uint32x4 s0 = *(const uint32x4*)(pb);
    uint32x4 s1 = *(const uint32x4*)(pb + 1024);
    uint32x4 s2 = *(const uint32x4*)(pb + 2048);
    uint32x4 s3 = *(const uint32x4*)(pb + 3072);
    for (int t = 0; t < 32; t += 2) {
        uint32x4 n0 = *(const uint32x4*)(pb + (t + 4) * 1024);
        uint32x4 n1 = *(const uint32x4*)(pb + (t + 5) * 1024);
        EXACT_TILE(s0, t)
        EXACT_TILE(s1, t + 1)
        s0 = s2; s1 = s3; s2 = n0; s3 = n1;
    }
}

// out[b,d,hw] = sum_f lat[f]*exp_w[d,f] + exp_b[d]; wave 0 of y==0 also does
// closest/hist/loss. Last-finished block (ticket) computes perplexity + finalize.
__global__ __launch_bounds__(256) void expand_out(const unsigned long long* __restrict__ keys64,
                                                  const float* __restrict__ EN, const float* __restrict__ ew,
                                                  const float* __restrict__ eb, const float* __restrict__ X,
                                                  float* __restrict__ out, float* __restrict__ closest_out,
                                                  int* __restrict__ counts, float* __restrict__ misc) {
    __shared__ float red[4];
    __shared__ int lastf;
    int lane = threadIdx.x & 63, wv = threadIdx.x >> 6;
    int p = blockIdx.x * 64 + lane;
    unsigned n = ~(unsigned)(keys64[p]);
    float lat[FF];
    const float4* l4 = (const float4*)(EN + (size_t)n * FF);
#pragma unroll
    for (int q = 0; q < 8; q++) {
        float4 v = l4[q];
        lat[q * 4] = v.x; lat[q * 4 + 1] = v.y; lat[q * 4 + 2] = v.z; lat[q * 4 + 3] = v.w;
    }
    if (blockIdx.y == 0 && wv == 0) {
        closest_out[p] = (float)n;
        atomicAdd(counts + n, 1);
        const float4* xr = (const float4*)(X + (size_t)p * FF);
        float s = 0.f;
#pragma unroll
        for (int q = 0; q < 8; q++) {
            float4 xv = xr[q];
            float dx = xv.x - lat[q * 4], dy = xv.y - lat[q * 4 + 1];
            float dz = xv.z - lat[q * 4 + 2], dw = xv.w - lat[q * 4 + 3];
            s += dx * dx + dy * dy + dz * dz + dw * dw;
        }
        for (int off = 32; off > 0; off >>= 1) s += __shfl_down(s, off);
        if (lane == 0) atomicAdd(misc, s);
    }
    int b = p >> 10, hw = p & 1023;
    float* op = out + (size_t)b * DD * HWS + hw;
    int d0 = blockIdx.y * 64 + wv * 16;
    for (int i = 0; i < 16; i++) {
        int d = d0 + i;
        const float4* w4 = (const float4*)(ew + (size_t)d * FF);
        float4 w0 = w4[0], w1 = w4[1], w2 = w4[2], w3 = w4[3];
        float4 w5 = w4[4], w6 = w4[5], w7 = w4[6], w8 = w4[7];
        float a0 = fmaf(lat[0], w0.x, eb[d]);
        float a1 = lat[1] * w0.y;
        float a2 = lat[2] * w0.z;
        float a3 = lat[3] * w0.w;
        a0 = fmaf(lat[4],  w1.x, a0); a1 = fmaf(lat[5],  w1.y, a1); a2 = fmaf(lat[6],  w1.z, a2); a3 = fmaf(lat[7],  w1.w, a3);
        a0 = fmaf(lat[8],  w2.x, a0); a1 = fmaf(lat[9],  w2.y, a1); a2 = fmaf(lat[10], w2.z, a2); a3 = fmaf(lat[11], w2.w, a3);
        a0 = fmaf(lat[12], w3.x, a0); a1 = fmaf(lat[13], w3.y, a1); a2 = fmaf(lat[14], w3.z, a2); a3 = fmaf(lat[15], w3.w, a3);
        a0 = fmaf(lat[16], w5.x, a0); a1 = fmaf(lat[17], w5.y, a1); a2 = fmaf(lat[18], w5.z, a2); a3 = fmaf(lat[19], w5.w, a3);
        a0 = fmaf(lat[20], w6.x, a0); a1 = fmaf(lat[21], w6.y, a1); a2 = fmaf(lat[22], w6.z, a2); a3 = fmaf(lat[23], w6.w, a3);
        a0 = fmaf(lat[24], w7.x, a0); a1 = fmaf(lat[25], w7.y, a1); a2 = fmaf(lat[26], w7.z, a2); a3 = fmaf(lat[27], w7.w, a3);
        a0 = fmaf(lat[28], w8.x, a0); a1 = fmaf(lat[29], w8.y, a1); a2 = fmaf(lat[30], w8.z, a2); a3 = fmaf(lat[31], w8.w, a3);
        op[(size_t)d * HWS] = (a0 + a1) + (a2 + a3);
    }
    // ---- done-ticket: last of the 1024 blocks computes perplexity + finalize ----
    __syncthreads();   // drains this block's vmcnt (atomics performed at coherent point)
    if (threadIdx.x == 0) {
        unsigned* done = (unsigned*)misc + 2;
        unsigned old = __hip_atomic_fetch_add(done, 1, __ATOMIC_RELAXED, __HIP_MEMORY_SCOPE_AGENT);
        lastf = (old == 1023) ? 1 : 0;
    }
    __syncthreads();
    if (lastf) {
        float s = 0.f;
#pragma unroll
        for (int r = 0; r < 64; r++) {
            int c = __hip_atomic_load(counts + threadIdx.x + r * 256, __ATOMIC_RELAXED, __HIP_MEMORY_SCOPE_AGENT);
            float u = (float)c * (1.0f / 8192.0f);
            s += u * logf(u + 1e-6f);
        }
        for (int off = 32; off > 0; off >>= 1) s += __shfl_down(s, off);
        if ((threadIdx.x & 63) == 0) red[threadIdx.x >> 6] = s;
        __syncthreads();
        if (threadIdx.x == 0) {
            float t = red[0] + red[1] + red[2] + red[3];
            float l = __hip_atomic_load(misc, __ATOMIC_RELAXED, __HIP_MEMORY_SCOPE_AGENT);
            out[4194304 + NPIX]     = l * (1.0f / 262144.0f);   // loss: mean over B*F*H*W
            out[4194304 + NPIX + 1] = expf(-t);                 // perplexity
        }
    }
}

extern "C" void kernel_launch(void* const* d_in, const int* in_sizes, int n_in,
                              void* d_out, int out_size, void* d_ws, size_t ws_size,
                              hipStream_t stream) {
    const float* enc = (const float*)d_in[0];
    const float* emb = (const float*)d_in[1];
    const float* pw  = (const float*)d_in[2];
    const float* pb  = (const float*)d_in[3];
    const float* ew  = (const float*)d_in[4];
    const float* eb  = (const float*)d_in[5];
    float* out = (float*)d_out;
    char* ws = (char*)d_ws;

    unsigned long long* keys64 = (unsigned long long*)(ws + WS_KEYS64);
    unsigned* keys32 = (unsigned*)(ws + WS_KEYS32);
    int*   counts = (int*)(ws + WS_COUNTS);
    float* misc   = (float*)(ws + WS_MISC);
    float* EN     = (float*)(ws + WS_EN);
    char*  EH     = ws + WS_EH;
    float* X      = (float*)(ws + WS_X);
    char*  XH     = ws + WS_XH;
    float* part   = (float*)(ws + WS_PART);

    prep_proj<<<576, 256, 0, stream>>>(pw, emb, enc, part, EN, EH, keys64, keys32, counts, (unsigned*)misc);
    finish_x<<<256, 256, 0, stream>>>(part, pb, X, XH);
    argmax_approx<<<dim3(32, 32), 256, 0, stream>>>((const uint32x4*)XH, EH, keys32);
    argmax_exact<<<dim3(32, 32), 256, 0, stream>>>((const uint32x4*)XH, EH, keys32, X, EN, keys64);
    expand_out<<<dim3(128, 8), 256, 0, stream>>>(keys64, EN, ew, eb, X, out, out + 4194304, counts, misc);
}

// Round 10
// 99.483 us; speedup vs baseline: 2.8624x; 1.0473x over previous
//
#include <hip/hip_runtime.h>
#include <math.h>

#define NPIX 8192
#define DD 512
#define FF 32
#define NN 16384
#define HWS 1024
#define DSPLIT 16
#define MARGIN 0.012f

// ws layout (bytes); ws_size ~256MB
#define WS_KEYS64 0         // 8192*8
#define WS_KEYS32 65536     // 8192*4
#define WS_COUNTS 98304     // 16384*4
#define WS_MISC   163840    // f32[0]=loss acc; u32[2]=done ticket (zeroed in prep)
#define WS_EN     229632    // 2 MB fp32 normalized codebook
#define WS_EH     2326784   // 1 MB tile-major bf16-h codebook (stream overread spills into WS_X: harmless)
#define WS_X      3375360   // 1 MB fp32 normalized x
#define WS_XH     4423936   // 512 KB bf16-h x fragments
#define WS_PART   4948224   // 16*8192*32*4 = 16 MB

typedef __bf16 bf16x8 __attribute__((ext_vector_type(8)));
typedef float f32x4 __attribute__((ext_vector_type(4)));
typedef unsigned int uint32x4 __attribute__((ext_vector_type(4)));

__device__ __forceinline__ unsigned short bf16_rne(float f) {
    unsigned u = __float_as_uint(f);
    u += 0x7fffu + ((u >> 16) & 1u);
    return (unsigned short)(u >> 16);
}
__device__ __forceinline__ f32x4 mfma16(bf16x8 a, bf16x8 b, f32x4 c) {
    return __builtin_amdgcn_mfma_f32_16x16x32_bf16(a, b, c, 0, 0, 0);
}
__device__ __forceinline__ unsigned mono_u32(float v) {
    unsigned u = __float_as_uint(v);
    return (u & 0x80000000u) ? ~u : (u | 0x80000000u);
}
__device__ __forceinline__ float mono_dec(unsigned u) {
    return __uint_as_float((u & 0x80000000u) ? (u ^ 0x80000000u) : ~u);
}
__device__ __forceinline__ unsigned long long packkey(float v, int n) {
    return ((unsigned long long)mono_u32(v) << 32) | (unsigned long long)(~(unsigned)n);
}

// Fused: blocks 0..255 = proj partials (pb = bx&15 -> 512 px, ds = bx>>4 -> 32 d),
// 2 px/thread (halves LDS-pipe instrs per FLOP vs R4);
// blocks 256..319 = codebook l2-norm (EN fp32 + EH bf16-h tile-major) + zero-init.
__global__ __launch_bounds__(256) void prep_proj(const float* __restrict__ pw, const float* __restrict__ emb,
                                                 const float* __restrict__ enc, float* __restrict__ part,
                                                 float* __restrict__ EN, char* __restrict__ EH,
                                                 unsigned long long* __restrict__ keys64,
                                                 unsigned* __restrict__ keys32, int* __restrict__ counts,
                                                 unsigned* __restrict__ misc_u) {
    int bx = blockIdx.x, tid = threadIdx.x;
    if (bx < 256) {
        __shared__ float lds[32 * FF];
        int pb = bx & 15, ds = bx >> 4;
        int d0 = ds * 32;
        for (int i = tid; i < 32 * FF; i += 256) {
            int dl = i >> 5, f = i & 31;
            lds[dl * FF + f] = pw[f * DD + d0 + dl];   // transpose folded into stage
        }
        __syncthreads();
        int px0 = pb * 512 + tid;                       // px1 = px0+256, same image
        int b = px0 >> 10, hw = px0 & 1023;
        const float* ep = enc + (size_t)b * DD * HWS + (size_t)d0 * HWS + hw;
        float acc0[FF], acc1[FF];
#pragma unroll
        for (int f = 0; f < FF; f++) { acc0[f] = 0.f; acc1[f] = 0.f; }
        float ev0[4], ev1[4];
#pragma unroll
        for (int j = 0; j < 4; j++) { ev0[j] = ep[(size_t)j * HWS]; ev1[j] = ep[(size_t)j * HWS + 256]; }
#pragma unroll
        for (int g = 0; g < 8; g++) {
            float nv0[4], nv1[4];
            if (g < 7) {
#pragma unroll
                for (int j = 0; j < 4; j++) {
                    nv0[j] = ep[(size_t)(g * 4 + 4 + j) * HWS];
                    nv1[j] = ep[(size_t)(g * 4 + 4 + j) * HWS + 256];
                }
            }
#pragma unroll
            for (int j = 0; j < 4; j++) {
                const float4* w4 = (const float4*)&lds[(g * 4 + j) * FF];
#pragma unroll
                for (int q = 0; q < 8; q++) {
                    float4 w = w4[q];
                    acc0[q * 4 + 0] = fmaf(ev0[j], w.x, acc0[q * 4 + 0]);
                    acc0[q * 4 + 1] = fmaf(ev0[j], w.y, acc0[q * 4 + 1]);
                    acc0[q * 4 + 2] = fmaf(ev0[j], w.z, acc0[q * 4 + 2]);
                    acc0[q * 4 + 3] = fmaf(ev0[j], w.w, acc0[q * 4 + 3]);
                    acc1[q * 4 + 0] = fmaf(ev1[j], w.x, acc1[q * 4 + 0]);
                    acc1[q * 4 + 1] = fmaf(ev1[j], w.y, acc1[q * 4 + 1]);
                    acc1[q * 4 + 2] = fmaf(ev1[j], w.z, acc1[q * 4 + 2]);
                    acc1[q * 4 + 3] = fmaf(ev1[j], w.w, acc1[q * 4 + 3]);
                }
            }
            if (g < 7) {
#pragma unroll
                for (int j = 0; j < 4; j++) { ev0[j] = nv0[j]; ev1[j] = nv1[j]; }
            }
        }
        float4* o0 = (float4*)(part + ((size_t)ds * NPIX + px0) * FF);
        float4* o1 = (float4*)(part + ((size_t)ds * NPIX + px0 + 256) * FF);
#pragma unroll
        for (int q = 0; q < 8; q++) {
            o0[q] = make_float4(acc0[q * 4], acc0[q * 4 + 1], acc0[q * 4 + 2], acc0[q * 4 + 3]);
            o1[q] = make_float4(acc1[q * 4], acc1[q * 4 + 1], acc1[q * 4 + 2], acc1[q * 4 + 3]);
        }
    } else {
        int i = (bx - 256) * 256 + tid;   // 0..16383
        counts[i] = 0;
        if (i < 8192) { keys64[i] = 0ull; keys32[i] = 0u; }
        if (i < 8) misc_u[i] = 0u;
        const float4* r = (const float4*)(emb + (size_t)i * FF);
        float e[FF];
        float s = 0.f;
#pragma unroll
        for (int q = 0; q < 8; q++) {
            float4 v = r[q];
            e[q * 4] = v.x; e[q * 4 + 1] = v.y; e[q * 4 + 2] = v.z; e[q * 4 + 3] = v.w;
            s += v.x * v.x + v.y * v.y + v.z * v.z + v.w * v.w;
        }
        float m = fmaxf(sqrtf(s), 1e-6f);
#pragma unroll
        for (int f = 0; f < FF; f++) e[f] = e[f] / m;
        float4* o = (float4*)(EN + (size_t)i * FF);
#pragma unroll
        for (int q = 0; q < 8; q++)
            o[q] = make_float4(e[q * 4], e[q * 4 + 1], e[q * 4 + 2], e[q * 4 + 3]);
        int g = i >> 4, rl = i & 15;
#pragma unroll
        for (int kg = 0; kg < 4; kg++) {
            unsigned hw_[4];
#pragma unroll
            for (int w = 0; w < 4; w++) {
                unsigned short h0 = bf16_rne(e[kg * 8 + w * 2]);
                unsigned short h1 = bf16_rne(e[kg * 8 + w * 2 + 1]);
                hw_[w] = (unsigned)h0 | ((unsigned)h1 << 16);
            }
            uint32x4 th = {hw_[0], hw_[1], hw_[2], hw_[3]};
            *(uint32x4*)(EH + (size_t)g * 1024 + (kg * 16 + rl) * 16) = th;
        }
    }
}

// Sum partials + bias, l2norm -> X fp32 + bf16-h XH. 8 threads/pixel (4 ch each), 256 blocks.
__global__ __launch_bounds__(256) void finish_x(const float* __restrict__ part, const float* __restrict__ pbias,
                                                float* __restrict__ X, char* __restrict__ XH) {
    int t = blockIdx.x * 256 + threadIdx.x;
    int p = t >> 3, q = t & 7;
    float ax = 0.f, ay = 0.f, az = 0.f, aw = 0.f;
    for (int sg = 0; sg < DSPLIT; sg++) {
        float4 v = *(const float4*)(part + ((size_t)sg * NPIX + p) * FF + q * 4);
        ax += v.x; ay += v.y; az += v.z; aw += v.w;
    }
    float4 bq = *(const float4*)(pbias + q * 4);
    ax += bq.x; ay += bq.y; az += bq.z; aw += bq.w;
    float ss = ax * ax + ay * ay + az * az + aw * aw;
    ss += __shfl_xor(ss, 1);
    ss += __shfl_xor(ss, 2);
    ss += __shfl_xor(ss, 4);
    float m = fmaxf(sqrtf(ss), 1e-6f);
    ax /= m; ay /= m; az /= m; aw /= m;
    *(float4*)(X + (size_t)p * FF + q * 4) = make_float4(ax, ay, az, aw);
    unsigned h0 = (unsigned)bf16_rne(ax) | ((unsigned)bf16_rne(ay) << 16);
    unsigned h1 = (unsigned)bf16_rne(az) | ((unsigned)bf16_rne(aw) << 16);
    *(uint2*)(XH + (size_t)p * 64 + q * 8) = make_uint2(h0, h1);
}

// Phase 1: approx sims (h.h only) -> per-pixel max value via u32 atomicMax. (R4-proven)
#define APPROX_TILE(S)                                          \
    {                                                           \
        bf16x8 bh = __builtin_bit_cast(bf16x8, S);              \
        f32x4 c0 = {0.f,0.f,0.f,0.f}, c1 = {0.f,0.f,0.f,0.f};   \
        f32x4 c2 = {0.f,0.f,0.f,0.f}, c3 = {0.f,0.f,0.f,0.f};   \
        c0 = mfma16(ah[0], bh, c0); c1 = mfma16(ah[1], bh, c1); \
        c2 = mfma16(ah[2], bh, c2); c3 = mfma16(ah[3], bh, c3); \
        _Pragma("unroll")                                       \
        for (int i = 0; i < 4; i++) {                           \
            bv[i]      = fmaxf(bv[i],      c0[i]);              \
            bv[4 + i]  = fmaxf(bv[4 + i],  c1[i]);              \
            bv[8 + i]  = fmaxf(bv[8 + i],  c2[i]);              \
            bv[12 + i] = fmaxf(bv[12 + i], c3[i]);              \
        }                                                       \
    }

__global__ __launch_bounds__(256) void argmax_approx(const uint32x4* __restrict__ XHp,
                                                     const char* __restrict__ EH,
                                                     unsigned* __restrict__ keys32) {
    int tid = threadIdx.x, lane = tid & 63, wv = tid >> 6;
    int rl = lane & 15, kg = lane >> 4;
    int wavebase = blockIdx.x * 256 + wv * 64;
    int nblk = blockIdx.y;
    bf16x8 ah[4];
#pragma unroll
    for (int m = 0; m < 4; m++)
        ah[m] = __builtin_bit_cast(bf16x8, XHp[(wavebase + m * 16 + rl) * 4 + kg]);
    const char* pb = EH + (size_t)nblk * 32768 + lane * 16;
    float bv[16];
#pragma unroll
    for (int j = 0; j < 16; j++) bv[j] = -3.0e38f;

    uint32x4 s0 = *(const uint32x4*)(pb);
    uint32x4 s1 = *(const uint32x4*)(pb + 1024);
    uint32x4 s2 = *(const uint32x4*)(pb + 2048);
    uint32x4 s3 = *(const uint32x4*)(pb + 3072);
    for (int t = 0; t < 32; t += 2) {
        uint32x4 n0 = *(const uint32x4*)(pb + (t + 4) * 1024);   // overread <=4KB: harmless
        uint32x4 n1 = *(const uint32x4*)(pb + (t + 5) * 1024);
        APPROX_TILE(s0)
        APPROX_TILE(s1)
        s0 = s2; s1 = s3; s2 = n0; s3 = n1;
    }
#pragma unroll
    for (int st = 1; st < 16; st <<= 1)
#pragma unroll
        for (int j = 0; j < 16; j++) bv[j] = fmaxf(bv[j], __shfl_xor(bv[j], st));
    if (rl == 0) {
#pragma unroll
        for (int j = 0; j < 16; j++)
            atomicMax(keys32 + wavebase + (j >> 2) * 16 + kg * 4 + (j & 3), mono_u32(bv[j]));
    }
}

// Phase 2: recompute approx; candidates (>= pixelmax - MARGIN) get exact fp32 dot. (R4-proven)
#define EXACT_TILE(S, T)                                                          \
    {                                                                             \
        bf16x8 bh = __builtin_bit_cast(bf16x8, S);                                \
        f32x4 c0 = {0.f,0.f,0.f,0.f}, c1 = {0.f,0.f,0.f,0.f};                     \
        f32x4 c2 = {0.f,0.f,0.f,0.f}, c3 = {0.f,0.f,0.f,0.f};                     \
        c0 = mfma16(ah[0], bh, c0); c1 = mfma16(ah[1], bh, c1);                   \
        c2 = mfma16(ah[2], bh, c2); c3 = mfma16(ah[3], bh, c3);                   \
        float dm = c0[0] - thr[0];                                                \
        _Pragma("unroll")                                                         \
        for (int i = 0; i < 4; i++) {                                             \
            dm = fmaxf(dm, c0[i] - thr[i]);                                       \
            dm = fmaxf(dm, c1[i] - thr[4 + i]);                                   \
            dm = fmaxf(dm, c2[i] - thr[8 + i]);                                   \
            dm = fmaxf(dm, c3[i] - thr[12 + i]);                                  \
        }                                                                         \
        if (dm >= 0.f) {                                                          \
            float av[16];                                                         \
            _Pragma("unroll")                                                     \
            for (int i = 0; i < 4; i++) {                                         \
                av[i] = c0[i]; av[4 + i] = c1[i];                                 \
                av[8 + i] = c2[i]; av[12 + i] = c3[i];                            \
            }                                                                     \
            _Pragma("unroll")                                                     \
            for (int j = 0; j < 16; j++) {                                        \
                if (av[j] >= thr[j]) {                                            \
                    int p = wavebase + (j >> 2) * 16 + kg * 4 + (j & 3);          \
                    int n = nblk * 512 + (T) * 16 + rl;                           \
                    const float4* xr = (const float4*)(X + (size_t)p * FF);       \
                    const float4* er = (const float4*)(EN + (size_t)n * FF);      \
                    float a0 = 0.f, a1 = 0.f, a2 = 0.f, a3 = 0.f;                 \
                    _Pragma("unroll")                                             \
                    for (int q = 0; q < 8; q++) {                                 \
                        float4 xv = xr[q], ev = er[q];                            \
                        a0 = fmaf(xv.x, ev.x, a0); a1 = fmaf(xv.y, ev.y, a1);     \
                        a2 = fmaf(xv.z, ev.z, a2); a3 = fmaf(xv.w, ev.w, a3);     \
                    }                                                             \
                    float v = (a0 + a1) + (a2 + a3);                              \
                    atomicMax(keys64 + p, packkey(v, n));                         \
                }                                                                 \
            }                                                                     \
        }                                                                         \
    }

__global__ __launch_bounds__(256) void argmax_exact(const uint32x4* __restrict__ XHp,
                                                    const char* __restrict__ EH,
                                                    const unsigned* __restrict__ keys32,
                                                    const float* __restrict__ X, const float* __restrict__ EN,
                                                    unsigned long long* __restrict__ keys64) {
    int tid = threadIdx.x, lane = tid & 63, wv = tid >> 6;
    int rl = lane & 15, kg = lane >> 4;
    int wavebase = blockIdx.x * 256 + wv * 64;
    int nblk = blockIdx.y;
    bf16x8 ah[4];
#pragma unroll
    for (int m = 0; m < 4; m++)
        ah[m] = __builtin_bit_cast(bf16x8, XHp[(wavebase + m * 16 + rl) * 4 + kg]);
    float thr[16];
#pragma unroll
    for (int j = 0; j < 16; j++)
        thr[j] = mono_dec(keys32[wavebase + (j >> 2) * 16 + kg * 4 + (j & 3)]) - MARGIN;
    const char* pb = EH + (size_t)nblk * 32768 + lane * 16;

    uint32x4 s0 = *(const uint32x4*)(pb);
    uint32x4 s1 = *(const uint32x4*)(pb + 1024);
    uint32x4 s2 = *(const uint32x4*)(pb + 2048);
    uint32x4 s3 = *(const uint32x4*)(pb + 3072);
    for (int t = 0; t < 32; t += 2) {
        uint32x4 n0 = *(const uint32x4*)(pb + (t + 4) * 1024);
        uint32x4 n1 = *(const uint32x4*)(pb + (t + 5) * 1024);
        EXACT_TILE(s0, t)
        EXACT_TILE(s1, t + 1)
        s0 = s2; s1 = s3; s2 = n0; s3 = n1;
    }
}

// out[b,d,hw] = sum_f lat[f]*exp_w[d,f] + exp_b[d]; wave 0 of y==0 also does
// closest/hist/loss. Last-finished block (ticket) computes perplexity + finalize.
__global__ __launch_bounds__(256) void expand_out(const unsigned long long* __restrict__ keys64,
                                                  const float* __restrict__ EN, const float* __restrict__ ew,
                                                  const float* __restrict__ eb, const float* __restrict__ X,
                                                  float* __restrict__ out, float* __restrict__ closest_out,
                                                  int* __restrict__ counts, float* __restrict__ misc) {
    __shared__ float red[4];
    __shared__ int lastf;
    int lane = threadIdx.x & 63, wv = threadIdx.x >> 6;
    int p = blockIdx.x * 64 + lane;
    unsigned n = ~(unsigned)(keys64[p]);
    float lat[FF];
    const float4* l4 = (const float4*)(EN + (size_t)n * FF);
#pragma unroll
    for (int q = 0; q < 8; q++) {
        float4 v = l4[q];
        lat[q * 4] = v.x; lat[q * 4 + 1] = v.y; lat[q * 4 + 2] = v.z; lat[q * 4 + 3] = v.w;
    }
    if (blockIdx.y == 0 && wv == 0) {
        closest_out[p] = (float)n;
        atomicAdd(counts + n, 1);
        const float4* xr = (const float4*)(X + (size_t)p * FF);
        float s = 0.f;
#pragma unroll
        for (int q = 0; q < 8; q++) {
            float4 xv = xr[q];
            float dx = xv.x - lat[q * 4], dy = xv.y - lat[q * 4 + 1];
            float dz = xv.z - lat[q * 4 + 2], dw = xv.w - lat[q * 4 + 3];
            s += dx * dx + dy * dy + dz * dz + dw * dw;
        }
        for (int off = 32; off > 0; off >>= 1) s += __shfl_down(s, off);
        if (lane == 0) atomicAdd(misc, s);
    }
    int b = p >> 10, hw = p & 1023;
    float* op = out + (size_t)b * DD * HWS + hw;
    int d0 = blockIdx.y * 64 + wv * 16;
    for (int i = 0; i < 16; i++) {
        int d = d0 + i;
        const float4* w4 = (const float4*)(ew + (size_t)d * FF);
        float4 w0 = w4[0], w1 = w4[1], w2 = w4[2], w3 = w4[3];
        float4 w5 = w4[4], w6 = w4[5], w7 = w4[6], w8 = w4[7];
        float a0 = fmaf(lat[0], w0.x, eb[d]);
        float a1 = lat[1] * w0.y;
        float a2 = lat[2] * w0.z;
        float a3 = lat[3] * w0.w;
        a0 = fmaf(lat[4],  w1.x, a0); a1 = fmaf(lat[5],  w1.y, a1); a2 = fmaf(lat[6],  w1.z, a2); a3 = fmaf(lat[7],  w1.w, a3);
        a0 = fmaf(lat[8],  w2.x, a0); a1 = fmaf(lat[9],  w2.y, a1); a2 = fmaf(lat[10], w2.z, a2); a3 = fmaf(lat[11], w2.w, a3);
        a0 = fmaf(lat[12], w3.x, a0); a1 = fmaf(lat[13], w3.y, a1); a2 = fmaf(lat[14], w3.z, a2); a3 = fmaf(lat[15], w3.w, a3);
        a0 = fmaf(lat[16], w5.x, a0); a1 = fmaf(lat[17], w5.y, a1); a2 = fmaf(lat[18], w5.z, a2); a3 = fmaf(lat[19], w5.w, a3);
        a0 = fmaf(lat[20], w6.x, a0); a1 = fmaf(lat[21], w6.y, a1); a2 = fmaf(lat[22], w6.z, a2); a3 = fmaf(lat[23], w6.w, a3);
        a0 = fmaf(lat[24], w7.x, a0); a1 = fmaf(lat[25], w7.y, a1); a2 = fmaf(lat[26], w7.z, a2); a3 = fmaf(lat[27], w7.w, a3);
        a0 = fmaf(lat[28], w8.x, a0); a1 = fmaf(lat[29], w8.y, a1); a2 = fmaf(lat[30], w8.z, a2); a3 = fmaf(lat[31], w8.w, a3);
        op[(size_t)d * HWS] = (a0 + a1) + (a2 + a3);
    }
    // ---- done-ticket: last of the 1024 blocks computes perplexity + finalize ----
    __syncthreads();
    if (threadIdx.x == 0) {
        unsigned* done = (unsigned*)misc + 2;
        unsigned old = __hip_atomic_fetch_add(done, 1, __ATOMIC_RELAXED, __HIP_MEMORY_SCOPE_AGENT);
        lastf = (old == 1023) ? 1 : 0;
    }
    __syncthreads();
    if (lastf) {
        float s = 0.f;
#pragma unroll
        for (int r = 0; r < 64; r++) {
            int c = __hip_atomic_load(counts + threadIdx.x + r * 256, __ATOMIC_RELAXED, __HIP_MEMORY_SCOPE_AGENT);
            float u = (float)c * (1.0f / 8192.0f);
            s += u * logf(u + 1e-6f);
        }
        for (int off = 32; off > 0; off >>= 1) s += __shfl_down(s, off);
        if ((threadIdx.x & 63) == 0) red[threadIdx.x >> 6] = s;
        __syncthreads();
        if (threadIdx.x == 0) {
            float t = red[0] + red[1] + red[2] + red[3];
            float l = __hip_atomic_load(misc, __ATOMIC_RELAXED, __HIP_MEMORY_SCOPE_AGENT);
            out[4194304 + NPIX]     = l * (1.0f / 262144.0f);   // loss: mean over B*F*H*W
            out[4194304 + NPIX + 1] = expf(-t);                 // perplexity
        }
    }
}

extern "C" void kernel_launch(void* const* d_in, const int* in_sizes, int n_in,
                              void* d_out, int out_size, void* d_ws, size_t ws_size,
                              hipStream_t stream) {
    const float* enc = (const float*)d_in[0];
    const float* emb = (const float*)d_in[1];
    const float* pw  = (const float*)d_in[2];
    const float* pb  = (const float*)d_in[3];
    const float* ew  = (const float*)d_in[4];
    const float* eb  = (const float*)d_in[5];
    float* out = (float*)d_out;
    char* ws = (char*)d_ws;

    unsigned long long* keys64 = (unsigned long long*)(ws + WS_KEYS64);
    unsigned* keys32 = (unsigned*)(ws + WS_KEYS32);
    int*   counts = (int*)(ws + WS_COUNTS);
    float* misc   = (float*)(ws + WS_MISC);
    float* EN     = (float*)(ws + WS_EN);
    char*  EH     = ws + WS_EH;
    float* X      = (float*)(ws + WS_X);
    char*  XH     = ws + WS_XH;
    float* part   = (float*)(ws + WS_PART);

    prep_proj<<<320, 256, 0, stream>>>(pw, emb, enc, part, EN, EH, keys64, keys32, counts, (unsigned*)misc);
    finish_x<<<256, 256, 0, stream>>>(part, pb, X, XH);
    argmax_approx<<<dim3(32, 32), 256, 0, stream>>>((const uint32x4*)XH, EH, keys32);
    argmax_exact<<<dim3(32, 32), 256, 0, stream>>>((const uint32x4*)XH, EH, keys32, X, EN, keys64);
    expand_out<<<dim3(128, 8), 256, 0, stream>>>(keys64, EN, ew, eb, X, out, out + 4194304, counts, misc);
}

// Round 11
// 97.470 us; speedup vs baseline: 2.9215x; 1.0207x over previous
//
#include <hip/hip_runtime.h>
#include <math.h>

#define NPIX 8192
#define DD 512
#define FF 32
#define NN 16384
#define HWS 1024
#define DSPLIT 16
#define MARGIN 0.012f

// ws layout (bytes); ws_size ~256MB
#define WS_KEYS64 0         // 8192*8
#define WS_KEYS32 65536     // 8192*4
#define WS_COUNTS 98304     // 16384*4
#define WS_MISC   163840    // f32[0]=loss acc; u32[2]=done ticket (zeroed in prep)
#define WS_EN     229632    // 2 MB fp32 normalized codebook
#define WS_EH     2326784   // 1 MB tile-major bf16-h codebook (stream overread spills into WS_X: harmless)
#define WS_X      3375360   // 1 MB fp32 normalized x
#define WS_XH     4423936   // 512 KB bf16-h x fragments
#define WS_PART   4948224   // 16*8192*32*4 = 16 MB

typedef __bf16 bf16x8 __attribute__((ext_vector_type(8)));
typedef float f32x4 __attribute__((ext_vector_type(4)));
typedef unsigned int uint32x4 __attribute__((ext_vector_type(4)));

__device__ __forceinline__ unsigned short bf16_rne(float f) {
    unsigned u = __float_as_uint(f);
    u += 0x7fffu + ((u >> 16) & 1u);
    return (unsigned short)(u >> 16);
}
__device__ __forceinline__ f32x4 mfma16(bf16x8 a, bf16x8 b, f32x4 c) {
    return __builtin_amdgcn_mfma_f32_16x16x32_bf16(a, b, c, 0, 0, 0);
}
__device__ __forceinline__ unsigned mono_u32(float v) {
    unsigned u = __float_as_uint(v);
    return (u & 0x80000000u) ? ~u : (u | 0x80000000u);
}
__device__ __forceinline__ float mono_dec(unsigned u) {
    return __uint_as_float((u & 0x80000000u) ? (u ^ 0x80000000u) : ~u);
}
__device__ __forceinline__ unsigned long long packkey(float v, int n) {
    return ((unsigned long long)mono_u32(v) << 32) | (unsigned long long)(~(unsigned)n);
}

// R4-proven config: blocks 0..511 = proj partials (pb = bx&31, ds = bx>>5, 32 d each,
// 1 px/thread, 2 blocks/CU); blocks 512..575 = codebook norm + zero-init.
__global__ __launch_bounds__(256) void prep_proj(const float* __restrict__ pw, const float* __restrict__ emb,
                                                 const float* __restrict__ enc, float* __restrict__ part,
                                                 float* __restrict__ EN, char* __restrict__ EH,
                                                 unsigned long long* __restrict__ keys64,
                                                 unsigned* __restrict__ keys32, int* __restrict__ counts,
                                                 unsigned* __restrict__ misc_u) {
    int bx = blockIdx.x, tid = threadIdx.x;
    if (bx < 512) {
        __shared__ float lds[32 * FF];
        int pb = bx & 31, ds = bx >> 5;
        int d0 = ds * 32;
        for (int i = tid; i < 32 * FF; i += 256) {
            int dl = i >> 5, f = i & 31;
            lds[dl * FF + f] = pw[f * DD + d0 + dl];   // transpose folded into stage
        }
        __syncthreads();
        int p = pb * 256 + tid;
        int b = p >> 10, hw = p & 1023;
        const float* ep = enc + (size_t)b * DD * HWS + (size_t)d0 * HWS + hw;
        float acc[FF];
#pragma unroll
        for (int f = 0; f < FF; f++) acc[f] = 0.f;
        float ev[4];
#pragma unroll
        for (int j = 0; j < 4; j++) ev[j] = ep[(size_t)j * HWS];
#pragma unroll
        for (int g = 0; g < 8; g++) {
            float nv[4];
            if (g < 7) {
#pragma unroll
                for (int j = 0; j < 4; j++) nv[j] = ep[(size_t)(g * 4 + 4 + j) * HWS];
            }
#pragma unroll
            for (int j = 0; j < 4; j++) {
                const float4* w4 = (const float4*)&lds[(g * 4 + j) * FF];
#pragma unroll
                for (int q = 0; q < 8; q++) {
                    float4 w = w4[q];
                    acc[q * 4 + 0] = fmaf(ev[j], w.x, acc[q * 4 + 0]);
                    acc[q * 4 + 1] = fmaf(ev[j], w.y, acc[q * 4 + 1]);
                    acc[q * 4 + 2] = fmaf(ev[j], w.z, acc[q * 4 + 2]);
                    acc[q * 4 + 3] = fmaf(ev[j], w.w, acc[q * 4 + 3]);
                }
            }
            if (g < 7) {
#pragma unroll
                for (int j = 0; j < 4; j++) ev[j] = nv[j];
            }
        }
        float4* o = (float4*)(part + ((size_t)ds * NPIX + p) * FF);
#pragma unroll
        for (int q = 0; q < 8; q++)
            o[q] = make_float4(acc[q * 4], acc[q * 4 + 1], acc[q * 4 + 2], acc[q * 4 + 3]);
    } else {
        int i = (bx - 512) * 256 + tid;   // 0..16383
        counts[i] = 0;
        if (i < 8192) { keys64[i] = 0ull; keys32[i] = 0u; }
        if (i < 8) misc_u[i] = 0u;
        const float4* r = (const float4*)(emb + (size_t)i * FF);
        float e[FF];
        float s = 0.f;
#pragma unroll
        for (int q = 0; q < 8; q++) {
            float4 v = r[q];
            e[q * 4] = v.x; e[q * 4 + 1] = v.y; e[q * 4 + 2] = v.z; e[q * 4 + 3] = v.w;
            s += v.x * v.x + v.y * v.y + v.z * v.z + v.w * v.w;
        }
        float m = fmaxf(sqrtf(s), 1e-6f);
#pragma unroll
        for (int f = 0; f < FF; f++) e[f] = e[f] / m;
        float4* o = (float4*)(EN + (size_t)i * FF);
#pragma unroll
        for (int q = 0; q < 8; q++)
            o[q] = make_float4(e[q * 4], e[q * 4 + 1], e[q * 4 + 2], e[q * 4 + 3]);
        int g = i >> 4, rl = i & 15;
#pragma unroll
        for (int kg = 0; kg < 4; kg++) {
            unsigned hw_[4];
#pragma unroll
            for (int w = 0; w < 4; w++) {
                unsigned short h0 = bf16_rne(e[kg * 8 + w * 2]);
                unsigned short h1 = bf16_rne(e[kg * 8 + w * 2 + 1]);
                hw_[w] = (unsigned)h0 | ((unsigned)h1 << 16);
            }
            uint32x4 th = {hw_[0], hw_[1], hw_[2], hw_[3]};
            *(uint32x4*)(EH + (size_t)g * 1024 + (kg * 16 + rl) * 16) = th;
        }
    }
}

// Sum partials + bias, l2norm -> X fp32 + bf16-h XH. 8 threads/pixel (4 ch each), 256 blocks.
__global__ __launch_bounds__(256) void finish_x(const float* __restrict__ part, const float* __restrict__ pbias,
                                                float* __restrict__ X, char* __restrict__ XH) {
    int t = blockIdx.x * 256 + threadIdx.x;
    int p = t >> 3, q = t & 7;
    float ax = 0.f, ay = 0.f, az = 0.f, aw = 0.f;
    for (int sg = 0; sg < DSPLIT; sg++) {
        float4 v = *(const float4*)(part + ((size_t)sg * NPIX + p) * FF + q * 4);
        ax += v.x; ay += v.y; az += v.z; aw += v.w;
    }
    float4 bq = *(const float4*)(pbias + q * 4);
    ax += bq.x; ay += bq.y; az += bq.z; aw += bq.w;
    float ss = ax * ax + ay * ay + az * az + aw * aw;
    ss += __shfl_xor(ss, 1);
    ss += __shfl_xor(ss, 2);
    ss += __shfl_xor(ss, 4);
    float m = fmaxf(sqrtf(ss), 1e-6f);
    ax /= m; ay /= m; az /= m; aw /= m;
    *(float4*)(X + (size_t)p * FF + q * 4) = make_float4(ax, ay, az, aw);
    unsigned h0 = (unsigned)bf16_rne(ax) | ((unsigned)bf16_rne(ay) << 16);
    unsigned h1 = (unsigned)bf16_rne(az) | ((unsigned)bf16_rne(aw) << 16);
    *(uint2*)(XH + (size_t)p * 64 + q * 8) = make_uint2(h0, h1);
}

// Phase 1: approx sims (h.h only) -> per-pixel max value via u32 atomicMax. (R4-proven)
#define APPROX_TILE(S)                                          \
    {                                                           \
        bf16x8 bh = __builtin_bit_cast(bf16x8, S);              \
        f32x4 c0 = {0.f,0.f,0.f,0.f}, c1 = {0.f,0.f,0.f,0.f};   \
        f32x4 c2 = {0.f,0.f,0.f,0.f}, c3 = {0.f,0.f,0.f,0.f};   \
        c0 = mfma16(ah[0], bh, c0); c1 = mfma16(ah[1], bh, c1); \
        c2 = mfma16(ah[2], bh, c2); c3 = mfma16(ah[3], bh, c3); \
        _Pragma("unroll")                                       \
        for (int i = 0; i < 4; i++) {                           \
            bv[i]      = fmaxf(bv[i],      c0[i]);              \
            bv[4 + i]  = fmaxf(bv[4 + i],  c1[i]);              \
            bv[8 + i]  = fmaxf(bv[8 + i],  c2[i]);              \
            bv[12 + i] = fmaxf(bv[12 + i], c3[i]);              \
        }                                                       \
    }

__global__ __launch_bounds__(256) void argmax_approx(const uint32x4* __restrict__ XHp,
                                                     const char* __restrict__ EH,
                                                     unsigned* __restrict__ keys32) {
    int tid = threadIdx.x, lane = tid & 63, wv = tid >> 6;
    int rl = lane & 15, kg = lane >> 4;
    int wavebase = blockIdx.x * 256 + wv * 64;
    int nblk = blockIdx.y;
    bf16x8 ah[4];
#pragma unroll
    for (int m = 0; m < 4; m++)
        ah[m] = __builtin_bit_cast(bf16x8, XHp[(wavebase + m * 16 + rl) * 4 + kg]);
    const char* pb = EH + (size_t)nblk * 32768 + lane * 16;
    float bv[16];
#pragma unroll
    for (int j = 0; j < 16; j++) bv[j] = -3.0e38f;

    uint32x4 s0 = *(const uint32x4*)(pb);
    uint32x4 s1 = *(const uint32x4*)(pb + 1024);
    uint32x4 s2 = *(const uint32x4*)(pb + 2048);
    uint32x4 s3 = *(const uint32x4*)(pb + 3072);
    for (int t = 0; t < 32; t += 2) {
        uint32x4 n0 = *(const uint32x4*)(pb + (t + 4) * 1024);   // overread <=4KB: harmless
        uint32x4 n1 = *(const uint32x4*)(pb + (t + 5) * 1024);
        APPROX_TILE(s0)
        APPROX_TILE(s1)
        s0 = s2; s1 = s3; s2 = n0; s3 = n1;
    }
#pragma unroll
    for (int st = 1; st < 16; st <<= 1)
#pragma unroll
        for (int j = 0; j < 16; j++) bv[j] = fmaxf(bv[j], __shfl_xor(bv[j], st));
    if (rl == 0) {
#pragma unroll
        for (int j = 0; j < 16; j++)
            atomicMax(keys32 + wavebase + (j >> 2) * 16 + kg * 4 + (j & 3), mono_u32(bv[j]));
    }
}

// Phase 2: recompute approx; candidates (>= pixelmax - MARGIN) get exact fp32 dot. (R4-proven)
#define EXACT_TILE(S, T)                                                          \
    {                                                                             \
        bf16x8 bh = __builtin_bit_cast(bf16x8, S);                                \
        f32x4 c0 = {0.f,0.f,0.f,0.f}, c1 = {0.f,0.f,0.f,0.f};                     \
        f32x4 c2 = {0.f,0.f,0.f,0.f}, c3 = {0.f,0.f,0.f,0.f};                     \
        c0 = mfma16(ah[0], bh, c0); c1 = mfma16(ah[1], bh, c1);                   \
        c2 = mfma16(ah[2], bh, c2); c3 = mfma16(ah[3], bh, c3);                   \
        float dm = c0[0] - thr[0];                                                \
        _Pragma("unroll")                                                         \
        for (int i = 0; i < 4; i++) {                                             \
            dm = fmaxf(dm, c0[i] - thr[i]);                                       \
            dm = fmaxf(dm, c1[i] - thr[4 + i]);                                   \
            dm = fmaxf(dm, c2[i] - thr[8 + i]);                                   \
            dm = fmaxf(dm, c3[i] - thr[12 + i]);                                  \
        }                                                                         \
        if (dm >= 0.f) {                                                          \
            float av[16];                                                         \
            _Pragma("unroll")                                                     \
            for (int i = 0; i < 4; i++) {                                         \
                av[i] = c0[i]; av[4 + i] = c1[i];                                 \
                av[8 + i] = c2[i]; av[12 + i] = c3[i];                            \
            }                                                                     \
            _Pragma("unroll")                                                     \
            for (int j = 0; j < 16; j++) {                                        \
                if (av[j] >= thr[j]) {                                            \
                    int p = wavebase + (j >> 2) * 16 + kg * 4 + (j & 3);          \
                    int n = nblk * 512 + (T) * 16 + rl;                           \
                    const float4* xr = (const float4*)(X + (size_t)p * FF);       \
                    const float4* er = (const float4*)(EN + (size_t)n * FF);      \
                    float a0 = 0.f, a1 = 0.f, a2 = 0.f, a3 = 0.f;                 \
                    _Pragma("unroll")                                             \
                    for (int q = 0; q < 8; q++) {                                 \
                        float4 xv = xr[q], ev = er[q];                            \
                        a0 = fmaf(xv.x, ev.x, a0); a1 = fmaf(xv.y, ev.y, a1);     \
                        a2 = fmaf(xv.z, ev.z, a2); a3 = fmaf(xv.w, ev.w, a3);     \
                    }                                                             \
                    float v = (a0 + a1) + (a2 + a3);                              \
                    atomicMax(keys64 + p, packkey(v, n));                         \
                }                                                                 \
            }                                                                     \
        }                                                                         \
    }

__global__ __launch_bounds__(256) void argmax_exact(const uint32x4* __restrict__ XHp,
                                                    const char* __restrict__ EH,
                                                    const unsigned* __restrict__ keys32,
                                                    const float* __restrict__ X, const float* __restrict__ EN,
                                                    unsigned long long* __restrict__ keys64) {
    int tid = threadIdx.x, lane = tid & 63, wv = tid >> 6;
    int rl = lane & 15, kg = lane >> 4;
    int wavebase = blockIdx.x * 256 + wv * 64;
    int nblk = blockIdx.y;
    bf16x8 ah[4];
#pragma unroll
    for (int m = 0; m < 4; m++)
        ah[m] = __builtin_bit_cast(bf16x8, XHp[(wavebase + m * 16 + rl) * 4 + kg]);
    float thr[16];
#pragma unroll
    for (int j = 0; j < 16; j++)
        thr[j] = mono_dec(keys32[wavebase + (j >> 2) * 16 + kg * 4 + (j & 3)]) - MARGIN;
    const char* pb = EH + (size_t)nblk * 32768 + lane * 16;

    uint32x4 s0 = *(const uint32x4*)(pb);
    uint32x4 s1 = *(const uint32x4*)(pb + 1024);
    uint32x4 s2 = *(const uint32x4*)(pb + 2048);
    uint32x4 s3 = *(const uint32x4*)(pb + 3072);
    for (int t = 0; t < 32; t += 2) {
        uint32x4 n0 = *(const uint32x4*)(pb + (t + 4) * 1024);
        uint32x4 n1 = *(const uint32x4*)(pb + (t + 5) * 1024);
        EXACT_TILE(s0, t)
        EXACT_TILE(s1, t + 1)
        s0 = s2; s1 = s3; s2 = n0; s3 = n1;
    }
}

// out[b,d,hw] = sum_f lat[f]*exp_w[d,f] + exp_b[d]; wave 0 of y==0 also does
// closest/hist/loss. Last-finished block (ticket) computes perplexity + finalize.
__global__ __launch_bounds__(256) void expand_out(const unsigned long long* __restrict__ keys64,
                                                  const float* __restrict__ EN, const float* __restrict__ ew,
                                                  const float* __restrict__ eb, const float* __restrict__ X,
                                                  float* __restrict__ out, float* __restrict__ closest_out,
                                                  int* __restrict__ counts, float* __restrict__ misc) {
    __shared__ float red[4];
    __shared__ int lastf;
    int lane = threadIdx.x & 63, wv = threadIdx.x >> 6;
    int p = blockIdx.x * 64 + lane;
    unsigned n = ~(unsigned)(keys64[p]);
    float lat[FF];
    const float4* l4 = (const float4*)(EN + (size_t)n * FF);
#pragma unroll
    for (int q = 0; q < 8; q++) {
        float4 v = l4[q];
        lat[q * 4] = v.x; lat[q * 4 + 1] = v.y; lat[q * 4 + 2] = v.z; lat[q * 4 + 3] = v.w;
    }
    if (blockIdx.y == 0 && wv == 0) {
        closest_out[p] = (float)n;
        atomicAdd(counts + n, 1);
        const float4* xr = (const float4*)(X + (size_t)p * FF);
        float s = 0.f;
#pragma unroll
        for (int q = 0; q < 8; q++) {
            float4 xv = xr[q];
            float dx = xv.x - lat[q * 4], dy = xv.y - lat[q * 4 + 1];
            float dz = xv.z - lat[q * 4 + 2], dw = xv.w - lat[q * 4 + 3];
            s += dx * dx + dy * dy + dz * dz + dw * dw;
        }
        for (int off = 32; off > 0; off >>= 1) s += __shfl_down(s, off);
        if (lane == 0) atomicAdd(misc, s);
    }
    int b = p >> 10, hw = p & 1023;
    float* op = out + (size_t)b * DD * HWS + hw;
    int d0 = blockIdx.y * 64 + wv * 16;
    for (int i = 0; i < 16; i++) {
        int d = d0 + i;
        const float4* w4 = (const float4*)(ew + (size_t)d * FF);
        float4 w0 = w4[0], w1 = w4[1], w2 = w4[2], w3 = w4[3];
        float4 w5 = w4[4], w6 = w4[5], w7 = w4[6], w8 = w4[7];
        float a0 = fmaf(lat[0], w0.x, eb[d]);
        float a1 = lat[1] * w0.y;
        float a2 = lat[2] * w0.z;
        float a3 = lat[3] * w0.w;
        a0 = fmaf(lat[4],  w1.x, a0); a1 = fmaf(lat[5],  w1.y, a1); a2 = fmaf(lat[6],  w1.z, a2); a3 = fmaf(lat[7],  w1.w, a3);
        a0 = fmaf(lat[8],  w2.x, a0); a1 = fmaf(lat[9],  w2.y, a1); a2 = fmaf(lat[10], w2.z, a2); a3 = fmaf(lat[11], w2.w, a3);
        a0 = fmaf(lat[12], w3.x, a0); a1 = fmaf(lat[13], w3.y, a1); a2 = fmaf(lat[14], w3.z, a2); a3 = fmaf(lat[15], w3.w, a3);
        a0 = fmaf(lat[16], w5.x, a0); a1 = fmaf(lat[17], w5.y, a1); a2 = fmaf(lat[18], w5.z, a2); a3 = fmaf(lat[19], w5.w, a3);
        a0 = fmaf(lat[20], w6.x, a0); a1 = fmaf(lat[21], w6.y, a1); a2 = fmaf(lat[22], w6.z, a2); a3 = fmaf(lat[23], w6.w, a3);
        a0 = fmaf(lat[24], w7.x, a0); a1 = fmaf(lat[25], w7.y, a1); a2 = fmaf(lat[26], w7.z, a2); a3 = fmaf(lat[27], w7.w, a3);
        a0 = fmaf(lat[28], w8.x, a0); a1 = fmaf(lat[29], w8.y, a1); a2 = fmaf(lat[30], w8.z, a2); a3 = fmaf(lat[31], w8.w, a3);
        op[(size_t)d * HWS] = (a0 + a1) + (a2 + a3);
    }
    // ---- done-ticket: last of the 1024 blocks computes perplexity + finalize ----
    __syncthreads();
    if (threadIdx.x == 0) {
        unsigned* done = (unsigned*)misc + 2;
        unsigned old = __hip_atomic_fetch_add(done, 1, __ATOMIC_RELAXED, __HIP_MEMORY_SCOPE_AGENT);
        lastf = (old == 1023) ? 1 : 0;
    }
    __syncthreads();
    if (lastf) {
        float s = 0.f;
#pragma unroll
        for (int r = 0; r < 64; r++) {
            int c = __hip_atomic_load(counts + threadIdx.x + r * 256, __ATOMIC_RELAXED, __HIP_MEMORY_SCOPE_AGENT);
            float u = (float)c * (1.0f / 8192.0f);
            s += u * logf(u + 1e-6f);
        }
        for (int off = 32; off > 0; off >>= 1) s += __shfl_down(s, off);
        if ((threadIdx.x & 63) == 0) red[threadIdx.x >> 6] = s;
        __syncthreads();
        if (threadIdx.x == 0) {
            float t = red[0] + red[1] + red[2] + red[3];
            float l = __hip_atomic_load(misc, __ATOMIC_RELAXED, __HIP_MEMORY_SCOPE_AGENT);
            out[4194304 + NPIX]     = l * (1.0f / 262144.0f);   // loss: mean over B*F*H*W
            out[4194304 + NPIX + 1] = expf(-t);                 // perplexity
        }
    }
}

extern "C" void kernel_launch(void* const* d_in, const int* in_sizes, int n_in,
                              void* d_out, int out_size, void* d_ws, size_t ws_size,
                              hipStream_t stream) {
    const float* enc = (const float*)d_in[0];
    const float* emb = (const float*)d_in[1];
    const float* pw  = (const float*)d_in[2];
    const float* pb  = (const float*)d_in[3];
    const float* ew  = (const float*)d_in[4];
    const float* eb  = (const float*)d_in[5];
    float* out = (float*)d_out;
    char* ws = (char*)d_ws;

    unsigned long long* keys64 = (unsigned long long*)(ws + WS_KEYS64);
    unsigned* keys32 = (unsigned*)(ws + WS_KEYS32);
    int*   counts = (int*)(ws + WS_COUNTS);
    float* misc   = (float*)(ws + WS_MISC);
    float* EN     = (float*)(ws + WS_EN);
    char*  EH     = ws + WS_EH;
    float* X      = (float*)(ws + WS_X);
    char*  XH     = ws + WS_XH;
    float* part   = (float*)(ws + WS_PART);

    prep_proj<<<576, 256, 0, stream>>>(pw, emb, enc, part, EN, EH, keys64, keys32, counts, (unsigned*)misc);
    finish_x<<<256, 256, 0, stream>>>(part, pb, X, XH);
    argmax_approx<<<dim3(32, 32), 256, 0, stream>>>((const uint32x4*)XH, EH, keys32);
    argmax_exact<<<dim3(32, 32), 256, 0, stream>>>((const uint32x4*)XH, EH, keys32, X, EN, keys64);
    expand_out<<<dim3(128, 8), 256, 0, stream>>>(keys64, EN, ew, eb, X, out, out + 4194304, counts, misc);
}

// Round 12
// 91.599 us; speedup vs baseline: 3.1088x; 1.0641x over previous
//
#include <hip/hip_runtime.h>
#include <math.h>

#define NPIX 8192
#define DD 512
#define FF 32
#define NN 16384
#define HWS 1024
#define DSPLIT 16
#define MARGIN 0.012f

// ws layout (bytes); ws_size ~256MB
#define WS_KEYS64 0         // 8192*8
#define WS_KEYS32 65536     // 8192*4
#define WS_COUNTS 98304     // 16384*4
#define WS_MISC   163840    // f32[0]=loss acc (zeroed in prep)
#define WS_EN     229632    // 2 MB fp32 normalized codebook
#define WS_EH     2326784   // 1 MB tile-major bf16-h codebook (stream overread spills into WS_X: harmless)
#define WS_X      3375360   // 1 MB fp32 normalized x
#define WS_XH     4423936   // 512 KB bf16-h x fragments
#define WS_PART   4948224   // 16*8192*32*4 = 16 MB

typedef __bf16 bf16x8 __attribute__((ext_vector_type(8)));
typedef float f32x4 __attribute__((ext_vector_type(4)));
typedef unsigned int uint32x4 __attribute__((ext_vector_type(4)));

__device__ __forceinline__ unsigned short bf16_rne(float f) {
    unsigned u = __float_as_uint(f);
    u += 0x7fffu + ((u >> 16) & 1u);
    return (unsigned short)(u >> 16);
}
__device__ __forceinline__ f32x4 mfma16(bf16x8 a, bf16x8 b, f32x4 c) {
    return __builtin_amdgcn_mfma_f32_16x16x32_bf16(a, b, c, 0, 0, 0);
}
__device__ __forceinline__ unsigned mono_u32(float v) {
    unsigned u = __float_as_uint(v);
    return (u & 0x80000000u) ? ~u : (u | 0x80000000u);
}
__device__ __forceinline__ float mono_dec(unsigned u) {
    return __uint_as_float((u & 0x80000000u) ? (u ^ 0x80000000u) : ~u);
}
__device__ __forceinline__ unsigned long long packkey(float v, int n) {
    return ((unsigned long long)mono_u32(v) << 32) | (unsigned long long)(~(unsigned)n);
}

// Fused: blocks 0..511 = partial projection (pb = bx&31, ds = bx>>5, 32 d each);
// blocks 512..575 = codebook l2-norm (EN fp32 + EH bf16-h tile-major) + zero-init.
__global__ __launch_bounds__(256) void prep_proj(const float* __restrict__ pw, const float* __restrict__ emb,
                                                 const float* __restrict__ enc, float* __restrict__ part,
                                                 float* __restrict__ EN, char* __restrict__ EH,
                                                 unsigned long long* __restrict__ keys64,
                                                 unsigned* __restrict__ keys32, int* __restrict__ counts,
                                                 unsigned* __restrict__ misc_u) {
    int bx = blockIdx.x;
    if (bx < 512) {
        __shared__ float lds[32 * FF];
        int pb = bx & 31, ds = bx >> 5;
        int d0 = ds * 32;
        for (int i = threadIdx.x; i < 32 * FF; i += 256) {
            int dl = i >> 5, f = i & 31;
            lds[dl * FF + f] = pw[f * DD + d0 + dl];   // transpose folded into stage
        }
        __syncthreads();
        int p = pb * 256 + threadIdx.x;
        int b = p >> 10, hw = p & 1023;
        const float* ep = enc + (size_t)b * DD * HWS + (size_t)d0 * HWS + hw;
        float acc[FF];
#pragma unroll
        for (int f = 0; f < FF; f++) acc[f] = 0.f;
        float ev[4];
#pragma unroll
        for (int j = 0; j < 4; j++) ev[j] = ep[(size_t)j * HWS];
#pragma unroll
        for (int g = 0; g < 8; g++) {
            float nv[4];
            if (g < 7) {
#pragma unroll
                for (int j = 0; j < 4; j++) nv[j] = ep[(size_t)(g * 4 + 4 + j) * HWS];
            }
#pragma unroll
            for (int j = 0; j < 4; j++) {
                const float4* w4 = (const float4*)&lds[(g * 4 + j) * FF];
#pragma unroll
                for (int q = 0; q < 8; q++) {
                    float4 w = w4[q];
                    acc[q * 4 + 0] = fmaf(ev[j], w.x, acc[q * 4 + 0]);
                    acc[q * 4 + 1] = fmaf(ev[j], w.y, acc[q * 4 + 1]);
                    acc[q * 4 + 2] = fmaf(ev[j], w.z, acc[q * 4 + 2]);
                    acc[q * 4 + 3] = fmaf(ev[j], w.w, acc[q * 4 + 3]);
                }
            }
            if (g < 7) {
#pragma unroll
                for (int j = 0; j < 4; j++) ev[j] = nv[j];
            }
        }
        float4* o = (float4*)(part + ((size_t)ds * NPIX + p) * FF);
#pragma unroll
        for (int q = 0; q < 8; q++)
            o[q] = make_float4(acc[q * 4], acc[q * 4 + 1], acc[q * 4 + 2], acc[q * 4 + 3]);
    } else {
        int i = (bx - 512) * 256 + threadIdx.x;   // 0..16383
        counts[i] = 0;
        if (i < 8192) { keys64[i] = 0ull; keys32[i] = 0u; }
        if (i < 8) misc_u[i] = 0u;
        const float4* r = (const float4*)(emb + (size_t)i * FF);
        float e[FF];
        float s = 0.f;
#pragma unroll
        for (int q = 0; q < 8; q++) {
            float4 v = r[q];
            e[q * 4] = v.x; e[q * 4 + 1] = v.y; e[q * 4 + 2] = v.z; e[q * 4 + 3] = v.w;
            s += v.x * v.x + v.y * v.y + v.z * v.z + v.w * v.w;
        }
        float m = fmaxf(sqrtf(s), 1e-6f);
#pragma unroll
        for (int f = 0; f < FF; f++) e[f] = e[f] / m;
        float4* o = (float4*)(EN + (size_t)i * FF);
#pragma unroll
        for (int q = 0; q < 8; q++)
            o[q] = make_float4(e[q * 4], e[q * 4 + 1], e[q * 4 + 2], e[q * 4 + 3]);
        int g = i >> 4, rl = i & 15;
#pragma unroll
        for (int kg = 0; kg < 4; kg++) {
            unsigned hw_[4];
#pragma unroll
            for (int w = 0; w < 4; w++) {
                unsigned short h0 = bf16_rne(e[kg * 8 + w * 2]);
                unsigned short h1 = bf16_rne(e[kg * 8 + w * 2 + 1]);
                hw_[w] = (unsigned)h0 | ((unsigned)h1 << 16);
            }
            uint32x4 th = {hw_[0], hw_[1], hw_[2], hw_[3]};
            *(uint32x4*)(EH + (size_t)g * 1024 + (kg * 16 + rl) * 16) = th;
        }
    }
}

// Sum partials + bias, l2norm -> X fp32 + bf16-h XH. 8 threads/pixel (4 ch each), 256 blocks.
__global__ __launch_bounds__(256) void finish_x(const float* __restrict__ part, const float* __restrict__ pbias,
                                                float* __restrict__ X, char* __restrict__ XH) {
    int t = blockIdx.x * 256 + threadIdx.x;
    int p = t >> 3, q = t & 7;
    float ax = 0.f, ay = 0.f, az = 0.f, aw = 0.f;
    for (int sg = 0; sg < DSPLIT; sg++) {
        float4 v = *(const float4*)(part + ((size_t)sg * NPIX + p) * FF + q * 4);
        ax += v.x; ay += v.y; az += v.z; aw += v.w;
    }
    float4 bq = *(const float4*)(pbias + q * 4);
    ax += bq.x; ay += bq.y; az += bq.z; aw += bq.w;
    float ss = ax * ax + ay * ay + az * az + aw * aw;
    ss += __shfl_xor(ss, 1);
    ss += __shfl_xor(ss, 2);
    ss += __shfl_xor(ss, 4);
    float m = fmaxf(sqrtf(ss), 1e-6f);
    ax /= m; ay /= m; az /= m; aw /= m;
    *(float4*)(X + (size_t)p * FF + q * 4) = make_float4(ax, ay, az, aw);
    unsigned h0 = (unsigned)bf16_rne(ax) | ((unsigned)bf16_rne(ay) << 16);
    unsigned h1 = (unsigned)bf16_rne(az) | ((unsigned)bf16_rne(aw) << 16);
    *(uint2*)(XH + (size_t)p * 64 + q * 8) = make_uint2(h0, h1);
}

// Phase 1: approx sims (h.h only) -> per-pixel max value via u32 atomicMax.
#define APPROX_TILE(S)                                          \
    {                                                           \
        bf16x8 bh = __builtin_bit_cast(bf16x8, S);              \
        f32x4 c0 = {0.f,0.f,0.f,0.f}, c1 = {0.f,0.f,0.f,0.f};   \
        f32x4 c2 = {0.f,0.f,0.f,0.f}, c3 = {0.f,0.f,0.f,0.f};   \
        c0 = mfma16(ah[0], bh, c0); c1 = mfma16(ah[1], bh, c1); \
        c2 = mfma16(ah[2], bh, c2); c3 = mfma16(ah[3], bh, c3); \
        _Pragma("unroll")                                       \
        for (int i = 0; i < 4; i++) {                           \
            bv[i]      = fmaxf(bv[i],      c0[i]);              \
            bv[4 + i]  = fmaxf(bv[4 + i],  c1[i]);              \
            bv[8 + i]  = fmaxf(bv[8 + i],  c2[i]);              \
            bv[12 + i] = fmaxf(bv[12 + i], c3[i]);              \
        }                                                       \
    }

__global__ __launch_bounds__(256) void argmax_approx(const uint32x4* __restrict__ XHp,
                                                     const char* __restrict__ EH,
                                                     unsigned* __restrict__ keys32) {
    int tid = threadIdx.x, lane = tid & 63, wv = tid >> 6;
    int rl = lane & 15, kg = lane >> 4;
    int wavebase = blockIdx.x * 256 + wv * 64;
    int nblk = blockIdx.y;
    bf16x8 ah[4];
#pragma unroll
    for (int m = 0; m < 4; m++)
        ah[m] = __builtin_bit_cast(bf16x8, XHp[(wavebase + m * 16 + rl) * 4 + kg]);
    const char* pb = EH + (size_t)nblk * 32768 + lane * 16;
    float bv[16];
#pragma unroll
    for (int j = 0; j < 16; j++) bv[j] = -3.0e38f;

    uint32x4 s0 = *(const uint32x4*)(pb);
    uint32x4 s1 = *(const uint32x4*)(pb + 1024);
    uint32x4 s2 = *(const uint32x4*)(pb + 2048);
    uint32x4 s3 = *(const uint32x4*)(pb + 3072);
    for (int t = 0; t < 32; t += 2) {
        uint32x4 n0 = *(const uint32x4*)(pb + (t + 4) * 1024);   // overread <=4KB: harmless
        uint32x4 n1 = *(const uint32x4*)(pb + (t + 5) * 1024);
        APPROX_TILE(s0)
        APPROX_TILE(s1)
        s0 = s2; s1 = s3; s2 = n0; s3 = n1;
    }
#pragma unroll
    for (int st = 1; st < 16; st <<= 1)
#pragma unroll
        for (int j = 0; j < 16; j++) bv[j] = fmaxf(bv[j], __shfl_xor(bv[j], st));
    if (rl == 0) {
#pragma unroll
        for (int j = 0; j < 16; j++)
            atomicMax(keys32 + wavebase + (j >> 2) * 16 + kg * 4 + (j & 3), mono_u32(bv[j]));
    }
}

// Phase 2: recompute approx; candidates (>= pixelmax - MARGIN) get exact fp32 dot.
#define EXACT_TILE(S, T)                                                          \
    {                                                                             \
        bf16x8 bh = __builtin_bit_cast(bf16x8, S);                                \
        f32x4 c0 = {0.f,0.f,0.f,0.f}, c1 = {0.f,0.f,0.f,0.f};                     \
        f32x4 c2 = {0.f,0.f,0.f,0.f}, c3 = {0.f,0.f,0.f,0.f};                     \
        c0 = mfma16(ah[0], bh, c0); c1 = mfma16(ah[1], bh, c1);                   \
        c2 = mfma16(ah[2], bh, c2); c3 = mfma16(ah[3], bh, c3);                   \
        float dm = c0[0] - thr[0];                                                \
        _Pragma("unroll")                                                         \
        for (int i = 0; i < 4; i++) {                                             \
            dm = fmaxf(dm, c0[i] - thr[i]);                                       \
            dm = fmaxf(dm, c1[i] - thr[4 + i]);                                   \
            dm = fmaxf(dm, c2[i] - thr[8 + i]);                                   \
            dm = fmaxf(dm, c3[i] - thr[12 + i]);                                  \
        }                                                                         \
        if (dm >= 0.f) {                                                          \
            float av[16];                                                         \
            _Pragma("unroll")                                                     \
            for (int i = 0; i < 4; i++) {                                         \
                av[i] = c0[i]; av[4 + i] = c1[i];                                 \
                av[8 + i] = c2[i]; av[12 + i] = c3[i];                            \
            }                                                                     \
            _Pragma("unroll")                                                     \
            for (int j = 0; j < 16; j++) {                                        \
                if (av[j] >= thr[j]) {                                            \
                    int p = wavebase + (j >> 2) * 16 + kg * 4 + (j & 3);          \
                    int n = nblk * 512 + (T) * 16 + rl;                           \
                    const float4* xr = (const float4*)(X + (size_t)p * FF);       \
                    const float4* er = (const float4*)(EN + (size_t)n * FF);      \
                    float a0 = 0.f, a1 = 0.f, a2 = 0.f, a3 = 0.f;                 \
                    _Pragma("unroll")                                             \
                    for (int q = 0; q < 8; q++) {                                 \
                        float4 xv = xr[q], ev = er[q];                            \
                        a0 = fmaf(xv.x, ev.x, a0); a1 = fmaf(xv.y, ev.y, a1);     \
                        a2 = fmaf(xv.z, ev.z, a2); a3 = fmaf(xv.w, ev.w, a3);     \
                    }                                                             \
                    float v = (a0 + a1) + (a2 + a3);                              \
                    atomicMax(keys64 + p, packkey(v, n));                         \
                }                                                                 \
            }                                                                     \
        }                                                                         \
    }

__global__ __launch_bounds__(256) void argmax_exact(const uint32x4* __restrict__ XHp,
                                                    const char* __restrict__ EH,
                                                    const unsigned* __restrict__ keys32,
                                                    const float* __restrict__ X, const float* __restrict__ EN,
                                                    unsigned long long* __restrict__ keys64) {
    int tid = threadIdx.x, lane = tid & 63, wv = tid >> 6;
    int rl = lane & 15, kg = lane >> 4;
    int wavebase = blockIdx.x * 256 + wv * 64;
    int nblk = blockIdx.y;
    bf16x8 ah[4];
#pragma unroll
    for (int m = 0; m < 4; m++)
        ah[m] = __builtin_bit_cast(bf16x8, XHp[(wavebase + m * 16 + rl) * 4 + kg]);
    float thr[16];
#pragma unroll
    for (int j = 0; j < 16; j++)
        thr[j] = mono_dec(keys32[wavebase + (j >> 2) * 16 + kg * 4 + (j & 3)]) - MARGIN;
    const char* pb = EH + (size_t)nblk * 32768 + lane * 16;

    uint32x4 s0 = *(const uint32x4*)(pb);
    uint32x4 s1 = *(const uint32x4*)(pb + 1024);
    uint32x4 s2 = *(const uint32x4*)(pb + 2048);
    uint32x4 s3 = *(const uint32x4*)(pb + 3072);
    for (int t = 0; t < 32; t += 2) {
        uint32x4 n0 = *(const uint32x4*)(pb + (t + 4) * 1024);
        uint32x4 n1 = *(const uint32x4*)(pb + (t + 5) * 1024);
        EXACT_TILE(s0, t)
        EXACT_TILE(s1, t + 1)
        s0 = s2; s1 = s3; s2 = n0; s3 = n1;
    }
}

// out[b,d,hw] = sum_f lat[f]*exp_w[d,f] + exp_b[d]. Wave wv==0 of y==0 also does
// closest/hist/loss (it already has n and lat).
__global__ __launch_bounds__(256) void expand_out(const unsigned long long* __restrict__ keys64,
                                                  const float* __restrict__ EN, const float* __restrict__ ew,
                                                  const float* __restrict__ eb, const float* __restrict__ X,
                                                  float* __restrict__ out, float* __restrict__ closest_out,
                                                  int* __restrict__ counts, float* __restrict__ misc) {
    int lane = threadIdx.x & 63, wv = threadIdx.x >> 6;
    int p = blockIdx.x * 64 + lane;
    unsigned n = ~(unsigned)(keys64[p]);
    float lat[FF];
    const float4* l4 = (const float4*)(EN + (size_t)n * FF);
#pragma unroll
    for (int q = 0; q < 8; q++) {
        float4 v = l4[q];
        lat[q * 4] = v.x; lat[q * 4 + 1] = v.y; lat[q * 4 + 2] = v.z; lat[q * 4 + 3] = v.w;
    }
    if (blockIdx.y == 0 && wv == 0) {
        closest_out[p] = (float)n;
        atomicAdd(counts + n, 1);
        const float4* xr = (const float4*)(X + (size_t)p * FF);
        float s = 0.f;
#pragma unroll
        for (int q = 0; q < 8; q++) {
            float4 xv = xr[q];
            float dx = xv.x - lat[q * 4], dy = xv.y - lat[q * 4 + 1];
            float dz = xv.z - lat[q * 4 + 2], dw = xv.w - lat[q * 4 + 3];
            s += dx * dx + dy * dy + dz * dz + dw * dw;
        }
        for (int off = 32; off > 0; off >>= 1) s += __shfl_down(s, off);
        if (lane == 0) atomicAdd(misc, s);
    }
    int b = p >> 10, hw = p & 1023;
    float* op = out + (size_t)b * DD * HWS + hw;
    int d0 = blockIdx.y * 64 + wv * 16;
    for (int i = 0; i < 16; i++) {
        int d = d0 + i;
        const float4* w4 = (const float4*)(ew + (size_t)d * FF);
        float4 w0 = w4[0], w1 = w4[1], w2 = w4[2], w3 = w4[3];
        float4 w5 = w4[4], w6 = w4[5], w7 = w4[6], w8 = w4[7];
        float a0 = fmaf(lat[0], w0.x, eb[d]);
        float a1 = lat[1] * w0.y;
        float a2 = lat[2] * w0.z;
        float a3 = lat[3] * w0.w;
        a0 = fmaf(lat[4],  w1.x, a0); a1 = fmaf(lat[5],  w1.y, a1); a2 = fmaf(lat[6],  w1.z, a2); a3 = fmaf(lat[7],  w1.w, a3);
        a0 = fmaf(lat[8],  w2.x, a0); a1 = fmaf(lat[9],  w2.y, a1); a2 = fmaf(lat[10], w2.z, a2); a3 = fmaf(lat[11], w2.w, a3);
        a0 = fmaf(lat[12], w3.x, a0); a1 = fmaf(lat[13], w3.y, a1); a2 = fmaf(lat[14], w3.z, a2); a3 = fmaf(lat[15], w3.w, a3);
        a0 = fmaf(lat[16], w5.x, a0); a1 = fmaf(lat[17], w5.y, a1); a2 = fmaf(lat[18], w5.z, a2); a3 = fmaf(lat[19], w5.w, a3);
        a0 = fmaf(lat[20], w6.x, a0); a1 = fmaf(lat[21], w6.y, a1); a2 = fmaf(lat[22], w6.z, a2); a3 = fmaf(lat[23], w6.w, a3);
        a0 = fmaf(lat[24], w7.x, a0); a1 = fmaf(lat[25], w7.y, a1); a2 = fmaf(lat[26], w7.z, a2); a3 = fmaf(lat[27], w7.w, a3);
        a0 = fmaf(lat[28], w8.x, a0); a1 = fmaf(lat[29], w8.y, a1); a2 = fmaf(lat[30], w8.z, a2); a3 = fmaf(lat[31], w8.w, a3);
        op[(size_t)d * HWS] = (a0 + a1) + (a2 + a3);
    }
}

__global__ __launch_bounds__(1024) void perp_final(const int* __restrict__ counts,
                                                   const float* __restrict__ misc, float* __restrict__ o) {
    __shared__ float red[16];
    float s = 0.f;
#pragma unroll
    for (int r = 0; r < 16; r++) {
        float u = (float)counts[threadIdx.x + r * 1024] * (1.0f / 8192.0f);
        s += u * logf(u + 1e-6f);
    }
    for (int off = 32; off > 0; off >>= 1) s += __shfl_down(s, off);
    if ((threadIdx.x & 63) == 0) red[threadIdx.x >> 6] = s;
    __syncthreads();
    if (threadIdx.x == 0) {
        float t = 0.f;
        for (int i = 0; i < 16; i++) t += red[i];
        o[0] = misc[0] * (1.0f / 262144.0f);   // mean over B*F*H*W
        o[1] = expf(-t);
    }
}

extern "C" void kernel_launch(void* const* d_in, const int* in_sizes, int n_in,
                              void* d_out, int out_size, void* d_ws, size_t ws_size,
                              hipStream_t stream) {
    const float* enc = (const float*)d_in[0];
    const float* emb = (const float*)d_in[1];
    const float* pw  = (const float*)d_in[2];
    const float* pb  = (const float*)d_in[3];
    const float* ew  = (const float*)d_in[4];
    const float* eb  = (const float*)d_in[5];
    float* out = (float*)d_out;
    char* ws = (char*)d_ws;

    unsigned long long* keys64 = (unsigned long long*)(ws + WS_KEYS64);
    unsigned* keys32 = (unsigned*)(ws + WS_KEYS32);
    int*   counts = (int*)(ws + WS_COUNTS);
    float* misc   = (float*)(ws + WS_MISC);
    float* EN     = (float*)(ws + WS_EN);
    char*  EH     = ws + WS_EH;
    float* X      = (float*)(ws + WS_X);
    char*  XH     = ws + WS_XH;
    float* part   = (float*)(ws + WS_PART);

    prep_proj<<<576, 256, 0, stream>>>(pw, emb, enc, part, EN, EH, keys64, keys32, counts, (unsigned*)misc);
    finish_x<<<256, 256, 0, stream>>>(part, pb, X, XH);
    argmax_approx<<<dim3(32, 32), 256, 0, stream>>>((const uint32x4*)XH, EH, keys32);
    argmax_exact<<<dim3(32, 32), 256, 0, stream>>>((const uint32x4*)XH, EH, keys32, X, EN, keys64);
    expand_out<<<dim3(128, 8), 256, 0, stream>>>(keys64, EN, ew, eb, X, out, out + 4194304, counts, misc);
    perp_final<<<1, 1024, 0, stream>>>(counts, misc, out + 4194304 + NPIX);
}